// Round 8
// baseline (2369.833 us; speedup 1.0000x reference)
//
#include <hip/hip_runtime.h>
#include <hip/hip_fp16.h>
#include <cstdint>
#include <cstddef>

// ---------------------------------------------------------------------------
// GIN (GINEConv x3) forward, f32.
//   h  = x@W_enc + b_enc                                  (gemm_enc -> w0)
//   CSR build (degree padded to even): hist -> scan(3-pass, padded) ->
//     scatter -> permute(sat = {src,att}) -> eabuild(f16, pair-interleaved)
//   per layer i (fused): block aggregates its 64 nodes into LDS, then
//     h_out = relu( relu(BN(z@W1+b1)) @ W2 + b2 )  (ping-pong w0/w1 -> d_out)
// ---------------------------------------------------------------------------

// ---- packed-f32x2 atomic with compile-safe fallback (fallback path only) ---
template <class T>
__device__ inline auto add2_impl(T* p, T v, int)
    -> decltype(unsafeAtomicAdd(p, v), void()) {
    unsafeAtomicAdd(p, v);
}
template <class T>
__device__ inline void add2_impl(T* p, T v, long) {
    unsafeAtomicAdd(&p->x, v.x);
    unsafeAtomicAdd(&p->y, v.y);
}
__device__ inline void atomic_add2(float* p, float x, float y) {
    add2_impl(reinterpret_cast<float2*>(p), make_float2(x, y), 0);
}

// ---------------------------------------------------------------------------
// CSR build
// ---------------------------------------------------------------------------
__global__ void zero_cnt(int* __restrict__ cnt, int N)
{
    int i = blockIdx.x * blockDim.x + threadIdx.x;
    if (i < N) cnt[i] = 0;
}

__global__ void hist_kernel(const int* __restrict__ ei, int* __restrict__ cnt, int E)
{
    int i = blockIdx.x * blockDim.x + threadIdx.x;
    const int st = gridDim.x * blockDim.x;
    for (; i < E; i += st) atomicAdd(&cnt[ei[E + i]], 1);
}

// ---- 3-pass scan over PADDED degrees (deg + (deg&1)): 1024 elems/block ----
__global__ __launch_bounds__(256) void scan_pass1(
    const int* __restrict__ cnt, int* __restrict__ bsum, int N)
{
    __shared__ int part[256];
    const int t = threadIdx.x;
    const int base = blockIdx.x * 1024 + t * 4;
    int s = 0;
#pragma unroll
    for (int j = 0; j < 4; ++j) {
        int idx = base + j;
        if (idx < N) { int v = cnt[idx]; s += v + (v & 1); }
    }
    part[t] = s;
    __syncthreads();
    for (int d = 128; d > 0; d >>= 1) {
        if (t < d) part[t] += part[t + d];
        __syncthreads();
    }
    if (t == 0) bsum[blockIdx.x] = part[0];
}

// serial scan of block sums; writes total padded slot count to off[N]
__global__ __launch_bounds__(256) void scan_pass2(
    int* __restrict__ bsum, int* __restrict__ off, int NB, int N)
{
    __shared__ int sb[1024];
    const int t = threadIdx.x;
    for (int i = t; i < NB; i += 256) sb[i] = bsum[i];
    __syncthreads();
    if (t == 0) {
        int run = 0;
        for (int i = 0; i < NB; ++i) { int v = sb[i]; sb[i] = run; run += v; }
        off[N] = run;          // total padded slots S
    }
    __syncthreads();
    for (int i = t; i < NB; i += 256) bsum[i] = sb[i];
}

__global__ __launch_bounds__(256) void scan_pass3(
    const int* __restrict__ cnt, const int* __restrict__ bsum,
    int* __restrict__ off, int* __restrict__ cur, int N)
{
    __shared__ int part[256];
    const int t = threadIdx.x;
    const int base = blockIdx.x * 1024 + t * 4;
    int pv[4]; int s = 0;
#pragma unroll
    for (int j = 0; j < 4; ++j) {
        int idx = base + j;
        int v = (idx < N) ? cnt[idx] : 0;
        pv[j] = v + (v & 1);
        s += pv[j];
    }
    part[t] = s;
    __syncthreads();
    for (int d = 1; d < 256; d <<= 1) {
        int x = (t >= d) ? part[t - d] : 0;
        __syncthreads();
        part[t] += x;
        __syncthreads();
    }
    int run = bsum[blockIdx.x] + part[t] - s;   // exclusive padded base
#pragma unroll
    for (int j = 0; j < 4; ++j) {
        int idx = base + j;
        if (idx < N) { off[idx] = run; cur[idx] = run; }
        run += pv[j];
    }
}

__global__ void scatter_kernel(const int* __restrict__ ei, int* __restrict__ cur,
                               int* __restrict__ eids, int E)
{
    int i = blockIdx.x * blockDim.x + threadIdx.x;
    const int st = gridDim.x * blockDim.x;
    for (; i < E; i += st) {
        int pos = atomicAdd(&cur[ei[E + i]], 1);
        eids[pos] = i;
    }
}

// sat[slot] = {src_as_float, att}; padding slots (eid<0) -> {0, 0}
__global__ void permute_sat(
    const int* __restrict__ ei, const float* __restrict__ eatten,
    const int* __restrict__ eids, const int* __restrict__ offN,
    float2* __restrict__ sat, int Scap)
{
    const int S = *offN;
    int i = blockIdx.x * blockDim.x + threadIdx.x;
    const int st = gridDim.x * blockDim.x;
    for (; i < Scap; i += st) {
        if (i >= S) break;
        const int eid = eids[i];
        float2 v;
        if (eid >= 0) { v.x = __int_as_float(ei[eid]); v.y = eatten[eid]; }
        else          { v.x = __int_as_float(0);       v.y = 0.f; }
        sat[i] = v;
    }
}

// ---------------------------------------------------------------------------
// eabuild: ea = edge_attr@W_ee + b_ee, f16 half2, PAIR-INTERLEAVED layout:
//   eab2[(slot>>1)*128 + lane*2 + (slot&1)]
// One block per 256 slots; padding slots write 0.
// ---------------------------------------------------------------------------
__global__ __launch_bounds__(256) void eabuild_staged(
    const int* __restrict__ eids, const float* __restrict__ eattr,
    const float* __restrict__ W_ee, const float* __restrict__ b_ee,
    const int* __restrict__ offN, uint32_t* __restrict__ eab2, int Scap)
{
    __shared__ int   se[256];
    __shared__ float sattr[256 * 16];
    const int t = threadIdx.x;
    const int lane = t & 63;
    const int wv = t >> 6;
    const int c = lane * 2;

    const int S = *offN;
    const int base = blockIdx.x * 256;
    const int n = min(256, S - base);
    if (n <= 0) return;

    float2 w[16];
#pragma unroll
    for (int k = 0; k < 16; ++k) w[k] = *(const float2*)&W_ee[k * 128 + c];
    const float2 bv = *(const float2*)&b_ee[c];

    if (t < n) se[t] = eids[base + t];
    __syncthreads();

    float4* sa4 = (float4*)sattr;
    const float4* ea4 = (const float4*)eattr;
    for (int i = t; i < n * 4; i += 256) {
        const int row = i >> 2, part = i & 3;
        const int eid = se[row];
        sa4[i] = (eid >= 0) ? ea4[(size_t)eid * 4 + part]
                            : make_float4(0.f, 0.f, 0.f, 0.f);
    }
    __syncthreads();

    for (int slot = wv; slot < n; slot += 4) {
        const int gs = base + slot;
        uint32_t out = 0;
        if (se[slot] >= 0) {
            const float4* sr = (const float4*)&sattr[slot * 16];
            float4 e0 = sr[0], e1 = sr[1], e2 = sr[2], e3 = sr[3];
            const float ef[16] = {e0.x, e0.y, e0.z, e0.w, e1.x, e1.y, e1.z, e1.w,
                                  e2.x, e2.y, e2.z, e2.w, e3.x, e3.y, e3.z, e3.w};
            float d0 = bv.x, d1 = bv.y;
#pragma unroll
            for (int k = 0; k < 16; ++k) {
                d0 = fmaf(ef[k], w[k].x, d0);
                d1 = fmaf(ef[k], w[k].y, d1);
            }
            __half2 hh = __floats2half2_rn(d0, d1);
            out = *reinterpret_cast<uint32_t*>(&hh);
        }
        eab2[(size_t)(gs >> 1) * 128 + lane * 2 + (gs & 1)] = out;
    }
}

// ---------------------------------------------------------------------------
// FUSED layer: agg (64 nodes -> LDS) + MLP (GEMM1+BN+ReLU+GEMM2+ReLU).
// Edge ranges are even-aligned and even-length; pair loads throughout.
// ---------------------------------------------------------------------------
__global__ __launch_bounds__(512, 4) void layer_fused(
    const float* __restrict__ h_in,
    const float2* __restrict__ sat, const uint32_t* __restrict__ eab2,
    const int* __restrict__ off,
    const float* __restrict__ W1, const float* __restrict__ b1,
    const float* __restrict__ gam, const float* __restrict__ bet,
    const float* __restrict__ mu, const float* __restrict__ var,
    const float* __restrict__ W2, const float* __restrict__ b2,
    float* __restrict__ h_out, const float* __restrict__ eps, int layer, int n)
{
    __shared__ float At[64][128];
    __shared__ float Wb[2][16][128];
    const int t = threadIdx.x;
    const int lane = t & 63;
    const int wv = t >> 6;
    const int c = lane * 2;
    const int row0 = blockIdx.x * 64;

    const float4* W14 = (const float4*)W1;
    ((float4*)&Wb[0][0][0])[t] = W14[t];

    // ---- phase A: aggregation (each wave: 8 nodes) ----
    const float sc = 1.0f + eps[layer];
    for (int r = wv; r < 64; r += 8) {
        const int v = row0 + r;
        if (v >= n) { *(float2*)&At[r][c] = make_float2(0.f, 0.f); continue; }
        const int e0 = off[v], e1 = off[v + 1];   // even-aligned, even length
        float a0 = 0.f, a1 = 0.f;
        int e = e0;
        for (; e + 8 <= e1; e += 8) {
            float4 sa[4];
#pragma unroll
            for (int j = 0; j < 4; ++j) sa[j] = *(const float4*)&sat[e + 2 * j];
            uint2 eb[4];
#pragma unroll
            for (int j = 0; j < 4; ++j)
                eb[j] = *(const uint2*)&eab2[(size_t)((e >> 1) + j) * 128 + lane * 2];
            float2 hv[8];
#pragma unroll
            for (int j = 0; j < 4; ++j) {
                hv[2 * j]     = *(const float2*)&h_in[(size_t)__float_as_int(sa[j].x) * 128 + c];
                hv[2 * j + 1] = *(const float2*)&h_in[(size_t)__float_as_int(sa[j].z) * 128 + c];
            }
#pragma unroll
            for (int j = 0; j < 4; ++j) {
                __half2 h0 = *reinterpret_cast<const __half2*>(&eb[j].x);
                a0 += fmaxf(hv[2 * j].x + __half2float(__low2half(h0)), 0.f) * sa[j].y;
                a1 += fmaxf(hv[2 * j].y + __half2float(__high2half(h0)), 0.f) * sa[j].y;
                __half2 h1 = *reinterpret_cast<const __half2*>(&eb[j].y);
                a0 += fmaxf(hv[2 * j + 1].x + __half2float(__low2half(h1)), 0.f) * sa[j].w;
                a1 += fmaxf(hv[2 * j + 1].y + __half2float(__high2half(h1)), 0.f) * sa[j].w;
            }
        }
        for (; e < e1; e += 2) {
            float4 sa = *(const float4*)&sat[e];
            uint2 eb = *(const uint2*)&eab2[(size_t)(e >> 1) * 128 + lane * 2];
            float2 h0 = *(const float2*)&h_in[(size_t)__float_as_int(sa.x) * 128 + c];
            float2 h1 = *(const float2*)&h_in[(size_t)__float_as_int(sa.z) * 128 + c];
            __half2 q0 = *reinterpret_cast<const __half2*>(&eb.x);
            a0 += fmaxf(h0.x + __half2float(__low2half(q0)), 0.f) * sa.y;
            a1 += fmaxf(h0.y + __half2float(__high2half(q0)), 0.f) * sa.y;
            __half2 q1 = *reinterpret_cast<const __half2*>(&eb.y);
            a0 += fmaxf(h1.x + __half2float(__low2half(q1)), 0.f) * sa.w;
            a1 += fmaxf(h1.y + __half2float(__high2half(q1)), 0.f) * sa.w;
        }
        const float2 hv = *(const float2*)&h_in[(size_t)v * 128 + c];
        At[r][c]     = fmaf(sc, hv.x, a0);
        At[r][c + 1] = fmaf(sc, hv.y, a1);
    }
    __syncthreads();

    // ---- phase B: GEMM1 ----
    const int tx = t & 31, ty = t >> 5;
    float acc[4][4] = {};
    for (int cc = 0; cc < 8; ++cc) {
        const int buf = cc & 1;
        float4 wnext;
        if (cc < 7) wnext = W14[(cc + 1) * 512 + t];
#pragma unroll
        for (int g = 0; g < 4; ++g) {
            float4 w4[4];
#pragma unroll
            for (int kk = 0; kk < 4; ++kk) w4[kk] = *(const float4*)&Wb[buf][g * 4 + kk][tx * 4];
#pragma unroll
            for (int r = 0; r < 4; ++r) {
                float4 a = *(const float4*)&At[ty * 4 + r][cc * 16 + g * 4];
                float ar[4] = {a.x, a.y, a.z, a.w};
#pragma unroll
                for (int kk = 0; kk < 4; ++kk) {
                    acc[r][0] = fmaf(ar[kk], w4[kk].x, acc[r][0]);
                    acc[r][1] = fmaf(ar[kk], w4[kk].y, acc[r][1]);
                    acc[r][2] = fmaf(ar[kk], w4[kk].z, acc[r][2]);
                    acc[r][3] = fmaf(ar[kk], w4[kk].w, acc[r][3]);
                }
            }
        }
        if (cc < 7) ((float4*)&Wb[buf ^ 1][0][0])[t] = wnext;
        __syncthreads();
    }

    // ---- BN + ReLU -> At, stage W2 chunk 0 ----
    const int c0 = tx * 4;
    const float4* W24 = (const float4*)W2;
    float4 w2pre = W24[t];
    {
        float b1v[4], scv[4], shv[4];
#pragma unroll
        for (int cl = 0; cl < 4; ++cl) {
            b1v[cl] = b1[c0 + cl];
            float s = gam[c0 + cl] * rsqrtf(var[c0 + cl] + 1e-5f);
            scv[cl] = s;
            shv[cl] = bet[c0 + cl] - mu[c0 + cl] * s;
        }
#pragma unroll
        for (int r = 0; r < 4; ++r) {
            float4 y;
            y.x = fmaxf(fmaf(acc[r][0] + b1v[0], scv[0], shv[0]), 0.f);
            y.y = fmaxf(fmaf(acc[r][1] + b1v[1], scv[1], shv[1]), 0.f);
            y.z = fmaxf(fmaf(acc[r][2] + b1v[2], scv[2], shv[2]), 0.f);
            y.w = fmaxf(fmaf(acc[r][3] + b1v[3], scv[3], shv[3]), 0.f);
            *(float4*)&At[ty * 4 + r][c0] = y;
            acc[r][0] = 0.f; acc[r][1] = 0.f; acc[r][2] = 0.f; acc[r][3] = 0.f;
        }
    }
    ((float4*)&Wb[0][0][0])[t] = w2pre;
    __syncthreads();

    // ---- GEMM2 ----
    for (int cc = 0; cc < 8; ++cc) {
        const int buf = cc & 1;
        float4 wnext;
        if (cc < 7) wnext = W24[(cc + 1) * 512 + t];
#pragma unroll
        for (int g = 0; g < 4; ++g) {
            float4 w4[4];
#pragma unroll
            for (int kk = 0; kk < 4; ++kk) w4[kk] = *(const float4*)&Wb[buf][g * 4 + kk][tx * 4];
#pragma unroll
            for (int r = 0; r < 4; ++r) {
                float4 a = *(const float4*)&At[ty * 4 + r][cc * 16 + g * 4];
                float ar[4] = {a.x, a.y, a.z, a.w};
#pragma unroll
                for (int kk = 0; kk < 4; ++kk) {
                    acc[r][0] = fmaf(ar[kk], w4[kk].x, acc[r][0]);
                    acc[r][1] = fmaf(ar[kk], w4[kk].y, acc[r][1]);
                    acc[r][2] = fmaf(ar[kk], w4[kk].z, acc[r][2]);
                    acc[r][3] = fmaf(ar[kk], w4[kk].w, acc[r][3]);
                }
            }
        }
        if (cc < 7) ((float4*)&Wb[buf ^ 1][0][0])[t] = wnext;
        __syncthreads();
    }

    float b2v[4];
#pragma unroll
    for (int cl = 0; cl < 4; ++cl) b2v[cl] = b2[c0 + cl];
#pragma unroll
    for (int r = 0; r < 4; ++r) {
        int row = row0 + ty * 4 + r;
        if (row < n) {
            float4 o;
            o.x = fmaxf(acc[r][0] + b2v[0], 0.f);
            o.y = fmaxf(acc[r][1] + b2v[1], 0.f);
            o.z = fmaxf(acc[r][2] + b2v[2], 0.f);
            o.w = fmaxf(acc[r][3] + b2v[3], 0.f);
            *(float4*)&h_out[(size_t)row * 128 + c0] = o;
        }
    }
}

// ---------------------------------------------------------------------------
// Encoder GEMM: h = A@W + b.
// ---------------------------------------------------------------------------
__global__ __launch_bounds__(512, 4) void gemm_enc(
    const float* __restrict__ A, const float* __restrict__ W,
    const float* __restrict__ bias, float* __restrict__ H, int n)
{
    __shared__ float At[64][128];
    __shared__ float Wb[2][16][128];
    const int t = threadIdx.x;
    const int tx = t & 31, ty = t >> 5;

    const int row0 = blockIdx.x * 64;
    const int nrows = min(64, n - row0);
    const int lim = nrows * 32;
    const float4* A4 = (const float4*)(A + (size_t)row0 * 128);
    float4* At4 = (float4*)&At[0][0];
#pragma unroll
    for (int i = 0; i < 4; ++i) {
        int idx = t + 512 * i;
        if (idx < lim) At4[idx] = A4[idx];
    }
    const float4* W4 = (const float4*)W;
    ((float4*)&Wb[0][0][0])[t] = W4[t];
    __syncthreads();

    float acc[4][4] = {};
    for (int c = 0; c < 8; ++c) {
        const int buf = c & 1;
        float4 wnext;
        if (c < 7) wnext = W4[(c + 1) * 512 + t];
#pragma unroll
        for (int g = 0; g < 4; ++g) {
            float4 w4[4];
#pragma unroll
            for (int kk = 0; kk < 4; ++kk) w4[kk] = *(const float4*)&Wb[buf][g * 4 + kk][tx * 4];
#pragma unroll
            for (int r = 0; r < 4; ++r) {
                float4 a = *(const float4*)&At[ty * 4 + r][c * 16 + g * 4];
                float ar[4] = {a.x, a.y, a.z, a.w};
#pragma unroll
                for (int kk = 0; kk < 4; ++kk) {
                    acc[r][0] = fmaf(ar[kk], w4[kk].x, acc[r][0]);
                    acc[r][1] = fmaf(ar[kk], w4[kk].y, acc[r][1]);
                    acc[r][2] = fmaf(ar[kk], w4[kk].z, acc[r][2]);
                    acc[r][3] = fmaf(ar[kk], w4[kk].w, acc[r][3]);
                }
            }
        }
        if (c < 7) ((float4*)&Wb[buf ^ 1][0][0])[t] = wnext;
        __syncthreads();
    }

    const int c0 = tx * 4;
    float bvv[4];
#pragma unroll
    for (int c = 0; c < 4; ++c) bvv[c] = bias[c0 + c];
#pragma unroll
    for (int r = 0; r < 4; ++r) {
        int row = row0 + ty * 4 + r;
        if (row < n) {
            float4 o;
            o.x = acc[r][0] + bvv[0]; o.y = acc[r][1] + bvv[1];
            o.z = acc[r][2] + bvv[2]; o.w = acc[r][3] + bvv[3];
            *(float4*)&H[(size_t)row * 128 + c0] = o;
        }
    }
}

// ---------------------------------------------------------------------------
// Last-resort fallback tier: scale_init + atomic edge kernel + gemm_mlp
// ---------------------------------------------------------------------------
__global__ void scale_init(const float* __restrict__ h, float* __restrict__ z,
                           const float* __restrict__ eps, int layer, int n4)
{
    const float s = 1.0f + eps[layer];
    int i = blockIdx.x * blockDim.x + threadIdx.x;
    const int stride = gridDim.x * blockDim.x;
    const float4* h4 = (const float4*)h;
    float4* z4 = (float4*)z;
    for (; i < n4; i += stride) {
        float4 v = h4[i];
        v.x *= s; v.y *= s; v.z *= s; v.w *= s;
        z4[i] = v;
    }
}

__global__ __launch_bounds__(256) void edge_atomic(
    const float* __restrict__ h, const int* __restrict__ ei,
    const float* __restrict__ eattr, const float* __restrict__ eatten,
    const float* __restrict__ W_ee, const float* __restrict__ b_ee,
    float* __restrict__ Z, int E)
{
    __shared__ float Wee[16][128];
    __shared__ float bee[128];
    const int t = threadIdx.x;
    const float4* We4 = (const float4*)W_ee;
    float4* Ws4 = (float4*)&Wee[0][0];
#pragma unroll
    for (int i = 0; i < 2; ++i) Ws4[t + 256 * i] = We4[t + 256 * i];
    if (t < 128) bee[t] = b_ee[t];
    __syncthreads();

    const int lane = t & 63;
    const int c = lane * 2;
    const long wid = (long)blockIdx.x * 4 + (t >> 6);
    const long nw = (long)gridDim.x * 4;
    for (long e = wid; e < E; e += nw) {
        const int src = ei[e];
        const int dst = ei[E + e];
        const float att = eatten[e];
        union { float4 v4[4]; float f[16]; } ea;
        const float4* eap = (const float4*)(eattr + e * 16);
        ea.v4[0] = eap[0]; ea.v4[1] = eap[1]; ea.v4[2] = eap[2]; ea.v4[3] = eap[3];
        float2 hv = *(const float2*)&h[(size_t)src * 128 + c];
        float e0 = bee[c], e1 = bee[c + 1];
#pragma unroll
        for (int k = 0; k < 16; ++k) {
            float2 w = *(const float2*)&Wee[k][c];
            e0 = fmaf(ea.f[k], w.x, e0);
            e1 = fmaf(ea.f[k], w.y, e1);
        }
        float m0 = fmaxf(hv.x + e0, 0.f) * att;
        float m1 = fmaxf(hv.y + e1, 0.f) * att;
        atomic_add2(&Z[(size_t)dst * 128 + c], m0, m1);
    }
}

__global__ __launch_bounds__(512, 4) void gemm_mlp(
    const float* __restrict__ Z,
    const float* __restrict__ W1, const float* __restrict__ b1,
    const float* __restrict__ gam, const float* __restrict__ bet,
    const float* __restrict__ mu, const float* __restrict__ var,
    const float* __restrict__ W2, const float* __restrict__ b2,
    float* __restrict__ H, int n)
{
    __shared__ float At[64][128];
    __shared__ float Wb[2][16][128];
    const int t = threadIdx.x;
    const int tx = t & 31, ty = t >> 5;

    const int row0 = blockIdx.x * 64;
    const int nrows = min(64, n - row0);
    const int lim = nrows * 32;
    const float4* Z4 = (const float4*)(Z + (size_t)row0 * 128);
    float4* At4 = (float4*)&At[0][0];
#pragma unroll
    for (int i = 0; i < 4; ++i) {
        int idx = t + 512 * i;
        if (idx < lim) At4[idx] = Z4[idx];
    }
    const float4* W14 = (const float4*)W1;
    ((float4*)&Wb[0][0][0])[t] = W14[t];
    __syncthreads();

    float acc[4][4] = {};
    for (int c = 0; c < 8; ++c) {
        const int buf = c & 1;
        float4 wnext;
        if (c < 7) wnext = W14[(c + 1) * 512 + t];
#pragma unroll
        for (int g = 0; g < 4; ++g) {
            float4 w4[4];
#pragma unroll
            for (int kk = 0; kk < 4; ++kk) w4[kk] = *(const float4*)&Wb[buf][g * 4 + kk][tx * 4];
#pragma unroll
            for (int r = 0; r < 4; ++r) {
                float4 a = *(const float4*)&At[ty * 4 + r][c * 16 + g * 4];
                float ar[4] = {a.x, a.y, a.z, a.w};
#pragma unroll
                for (int kk = 0; kk < 4; ++kk) {
                    acc[r][0] = fmaf(ar[kk], w4[kk].x, acc[r][0]);
                    acc[r][1] = fmaf(ar[kk], w4[kk].y, acc[r][1]);
                    acc[r][2] = fmaf(ar[kk], w4[kk].z, acc[r][2]);
                    acc[r][3] = fmaf(ar[kk], w4[kk].w, acc[r][3]);
                }
            }
        }
        if (c < 7) ((float4*)&Wb[buf ^ 1][0][0])[t] = wnext;
        __syncthreads();
    }

    const int c0 = tx * 4;
    const float4* W24 = (const float4*)W2;
    float4 w2pre = W24[t];
    {
        float b1v[4], scv[4], shv[4];
#pragma unroll
        for (int cl = 0; cl < 4; ++cl) {
            b1v[cl] = b1[c0 + cl];
            float s = gam[c0 + cl] * rsqrtf(var[c0 + cl] + 1e-5f);
            scv[cl] = s;
            shv[cl] = bet[c0 + cl] - mu[c0 + cl] * s;
        }
#pragma unroll
        for (int r = 0; r < 4; ++r) {
            float4 y;
            y.x = fmaxf(fmaf(acc[r][0] + b1v[0], scv[0], shv[0]), 0.f);
            y.y = fmaxf(fmaf(acc[r][1] + b1v[1], scv[1], shv[1]), 0.f);
            y.z = fmaxf(fmaf(acc[r][2] + b1v[2], scv[2], shv[2]), 0.f);
            y.w = fmaxf(fmaf(acc[r][3] + b1v[3], scv[3], shv[3]), 0.f);
            *(float4*)&At[ty * 4 + r][c0] = y;
            acc[r][0] = 0.f; acc[r][1] = 0.f; acc[r][2] = 0.f; acc[r][3] = 0.f;
        }
    }
    ((float4*)&Wb[0][0][0])[t] = w2pre;
    __syncthreads();

    for (int c = 0; c < 8; ++c) {
        const int buf = c & 1;
        float4 wnext;
        if (c < 7) wnext = W24[(c + 1) * 512 + t];
#pragma unroll
        for (int g = 0; g < 4; ++g) {
            float4 w4[4];
#pragma unroll
            for (int kk = 0; kk < 4; ++kk) w4[kk] = *(const float4*)&Wb[buf][g * 4 + kk][tx * 4];
#pragma unroll
            for (int r = 0; r < 4; ++r) {
                float4 a = *(const float4*)&At[ty * 4 + r][c * 16 + g * 4];
                float ar[4] = {a.x, a.y, a.z, a.w};
#pragma unroll
                for (int kk = 0; kk < 4; ++kk) {
                    acc[r][0] = fmaf(ar[kk], w4[kk].x, acc[r][0]);
                    acc[r][1] = fmaf(ar[kk], w4[kk].y, acc[r][1]);
                    acc[r][2] = fmaf(ar[kk], w4[kk].z, acc[r][2]);
                    acc[r][3] = fmaf(ar[kk], w4[kk].w, acc[r][3]);
                }
            }
        }
        if (c < 7) ((float4*)&Wb[buf ^ 1][0][0])[t] = wnext;
        __syncthreads();
    }

    float b2v[4];
#pragma unroll
    for (int cl = 0; cl < 4; ++cl) b2v[cl] = b2[c0 + cl];
#pragma unroll
    for (int r = 0; r < 4; ++r) {
        int row = row0 + ty * 4 + r;
        if (row < n) {
            float4 o;
            o.x = fmaxf(acc[r][0] + b2v[0], 0.f);
            o.y = fmaxf(acc[r][1] + b2v[1], 0.f);
            o.z = fmaxf(acc[r][2] + b2v[2], 0.f);
            o.w = fmaxf(acc[r][3] + b2v[3], 0.f);
            *(float4*)&H[(size_t)row * 128 + c0] = o;
        }
    }
}

extern "C" void kernel_launch(void* const* d_in, const int* in_sizes, int n_in,
                              void* d_out, int out_size, void* d_ws, size_t ws_size,
                              hipStream_t stream)
{
    const float* x      = (const float*)d_in[0];
    const int*   ei     = (const int*)d_in[1];
    // d_in[2] = batch (unused)
    const float* eattr  = (const float*)d_in[3];
    const float* eatten = (const float*)d_in[4];
    const float* W_enc  = (const float*)d_in[5];
    const float* b_enc  = (const float*)d_in[6];
    const float* W_ee   = (const float*)d_in[7];
    const float* b_ee   = (const float*)d_in[8];
    const float* eps    = (const float*)d_in[9];
    const float* W1     = (const float*)d_in[10];
    const float* b1     = (const float*)d_in[11];
    const float* gam    = (const float*)d_in[12];
    const float* bet    = (const float*)d_in[13];
    const float* mu     = (const float*)d_in[14];
    const float* var    = (const float*)d_in[15];
    const float* W2     = (const float*)d_in[16];
    const float* b2     = (const float*)d_in[17];

    const int N = in_sizes[0] / 128;
    const int E = in_sizes[1] / 2;
    const int L = in_sizes[9];
    const int Scap = E + N;      // max padded slots

    float* hout = (float*)d_out;   // [N,128]

    // workspace layout
    const size_t hbytes = ((size_t)N * 128 * 4 + 255) & ~(size_t)255;
    char* p = (char*)d_ws;
    float* w0 = (float*)p;              p += hbytes;
    float* w1 = (float*)p;              p += hbytes;
    int* off  = (int*)p;                p += 4 * (size_t)(N + 1);
    int* cur  = (int*)p;                p += 4 * (size_t)N;
    int* cnt  = (int*)p;                p += 4 * (size_t)N;
    int* bsum = (int*)p;                p += 4 * 1024;
    int* eids = (int*)p;                p += 4 * (size_t)Scap;
    p = (char*)(((uintptr_t)p + 255) & ~(uintptr_t)255);
    float2* sat = (float2*)p;           p += 8 * (size_t)Scap;
    p = (char*)(((uintptr_t)p + 255) & ~(uintptr_t)255);
    uint32_t* eab2 = (uint32_t*)p;      p += 256 * (size_t)((Scap + 1) / 2) * 2;
    const size_t need_fused = (size_t)(p - (char*)d_ws);

    const bool use_fused = ws_size >= need_fused;
    const int tiles = (N + 63) / 64;
    const int NB = (N + 1023) / 1024;

    if (use_fused) {
        zero_cnt<<<(N + 255) / 256, 256, 0, stream>>>(cnt, N);
        hist_kernel<<<1024, 256, 0, stream>>>(ei, cnt, E);
        scan_pass1<<<NB, 256, 0, stream>>>(cnt, bsum, N);
        scan_pass2<<<1, 256, 0, stream>>>(bsum, off, NB, N);
        scan_pass3<<<NB, 256, 0, stream>>>(cnt, bsum, off, cur, N);
        hipMemsetAsync(eids, 0xFF, 4 * (size_t)Scap, stream);   // eids = -1
        scatter_kernel<<<1024, 256, 0, stream>>>(ei, cur, eids, E);
        permute_sat<<<1024, 256, 0, stream>>>(ei, eatten, eids, off + N, sat, Scap);
        eabuild_staged<<<(Scap + 255) / 256, 256, 0, stream>>>(
            eids, eattr, W_ee, b_ee, off + N, eab2, Scap);

        gemm_enc<<<tiles, 512, 0, stream>>>(x, W_enc, b_enc, w0, N);
        float* bufs[2] = {w0, w1};
        for (int i = 0; i < L; ++i) {
            const float* hin = bufs[i & 1];
            float* ho = (i == L - 1) ? hout : bufs[(i + 1) & 1];
            layer_fused<<<tiles, 512, 0, stream>>>(
                hin, sat, eab2, off,
                W1 + (size_t)i * 128 * 128, b1 + i * 128,
                gam + i * 128, bet + i * 128, mu + i * 128, var + i * 128,
                W2 + (size_t)i * 128 * 128, b2 + i * 128,
                ho, eps, i, N);
        }
        return;
    }

    // fallback: h in d_out, zbuf = w0
    float* h = hout;
    float* zbuf = w0;
    gemm_enc<<<tiles, 512, 0, stream>>>(x, W_enc, b_enc, h, N);
    for (int i = 0; i < L; ++i) {
        scale_init<<<2048, 256, 0, stream>>>(h, zbuf, eps, i, N * 128 / 4);
        edge_atomic<<<2048, 256, 0, stream>>>(h, ei, eattr, eatten, W_ee, b_ee, zbuf, E);
        gemm_mlp<<<tiles, 512, 0, stream>>>(
            zbuf, W1 + (size_t)i * 128 * 128, b1 + i * 128,
            gam + i * 128, bet + i * 128, mu + i * 128, var + i * 128,
            W2 + (size_t)i * 128 * 128, b2 + i * 128,
            h, N);
    }
}

// Round 9
// 868.557 us; speedup vs baseline: 2.7285x; 2.7285x over previous
//
#include <hip/hip_runtime.h>
#include <hip/hip_fp16.h>
#include <cstdint>
#include <cstddef>

// ---------------------------------------------------------------------------
// GIN (GINEConv x3) forward, f32.
//   h  = x@W_enc + b_enc                                  (gemm_enc)
//   CSR build (degree padded to even): hist -> scan(3-pass, padded) ->
//     fill(-1) -> scatter -> permute(sat={src,att}) -> eabuild(f16 pair-interleaved)
//   per layer i (fused): block aggregates its 64 nodes into LDS, then
//     h_out = relu( relu(BN(z@W1+b1)) @ W2 + b2 )
//   h ping-pongs between w0 (ws) and d_out; final layer lands in d_out.
// ---------------------------------------------------------------------------

// ---- packed-f32x2 atomic with compile-safe fallback (fallback path only) ---
template <class T>
__device__ inline auto add2_impl(T* p, T v, int)
    -> decltype(unsafeAtomicAdd(p, v), void()) {
    unsafeAtomicAdd(p, v);
}
template <class T>
__device__ inline void add2_impl(T* p, T v, long) {
    unsafeAtomicAdd(&p->x, v.x);
    unsafeAtomicAdd(&p->y, v.y);
}
__device__ inline void atomic_add2(float* p, float x, float y) {
    add2_impl(reinterpret_cast<float2*>(p), make_float2(x, y), 0);
}

// ---------------------------------------------------------------------------
// CSR build
// ---------------------------------------------------------------------------
__global__ void zero_cnt(int* __restrict__ cnt, int N)
{
    int i = blockIdx.x * blockDim.x + threadIdx.x;
    if (i < N) cnt[i] = 0;
}

__global__ void fill_neg1(int* __restrict__ a, int n)
{
    int i = blockIdx.x * blockDim.x + threadIdx.x;
    const int st = gridDim.x * blockDim.x;
    for (; i < n; i += st) a[i] = -1;
}

__global__ void hist_kernel(const int* __restrict__ ei, int* __restrict__ cnt, int E)
{
    int i = blockIdx.x * blockDim.x + threadIdx.x;
    const int st = gridDim.x * blockDim.x;
    for (; i < E; i += st) atomicAdd(&cnt[ei[E + i]], 1);
}

// ---- 3-pass scan over PADDED degrees (deg + (deg&1)): 1024 elems/block ----
__global__ __launch_bounds__(256) void scan_pass1(
    const int* __restrict__ cnt, int* __restrict__ bsum, int N)
{
    __shared__ int part[256];
    const int t = threadIdx.x;
    const int base = blockIdx.x * 1024 + t * 4;
    int s = 0;
#pragma unroll
    for (int j = 0; j < 4; ++j) {
        int idx = base + j;
        if (idx < N) { int v = cnt[idx]; s += v + (v & 1); }
    }
    part[t] = s;
    __syncthreads();
    for (int d = 128; d > 0; d >>= 1) {
        if (t < d) part[t] += part[t + d];
        __syncthreads();
    }
    if (t == 0) bsum[blockIdx.x] = part[0];
}

// serial scan of block sums; writes total padded slot count to off[N]
__global__ __launch_bounds__(256) void scan_pass2(
    int* __restrict__ bsum, int* __restrict__ off, int NB, int N)
{
    __shared__ int sb[1024];
    const int t = threadIdx.x;
    for (int i = t; i < NB; i += 256) sb[i] = bsum[i];
    __syncthreads();
    if (t == 0) {
        int run = 0;
        for (int i = 0; i < NB; ++i) { int v = sb[i]; sb[i] = run; run += v; }
        off[N] = run;          // total padded slots S
    }
    __syncthreads();
    for (int i = t; i < NB; i += 256) bsum[i] = sb[i];
}

__global__ __launch_bounds__(256) void scan_pass3(
    const int* __restrict__ cnt, const int* __restrict__ bsum,
    int* __restrict__ off, int* __restrict__ cur, int N)
{
    __shared__ int part[256];
    const int t = threadIdx.x;
    const int base = blockIdx.x * 1024 + t * 4;
    int pv[4]; int s = 0;
#pragma unroll
    for (int j = 0; j < 4; ++j) {
        int idx = base + j;
        int v = (idx < N) ? cnt[idx] : 0;
        pv[j] = v + (v & 1);
        s += pv[j];
    }
    part[t] = s;
    __syncthreads();
    for (int d = 1; d < 256; d <<= 1) {
        int x = (t >= d) ? part[t - d] : 0;
        __syncthreads();
        part[t] += x;
        __syncthreads();
    }
    int run = bsum[blockIdx.x] + part[t] - s;   // exclusive padded base
#pragma unroll
    for (int j = 0; j < 4; ++j) {
        int idx = base + j;
        if (idx < N) { off[idx] = run; cur[idx] = run; }
        run += pv[j];
    }
}

__global__ void scatter_kernel(const int* __restrict__ ei, int* __restrict__ cur,
                               int* __restrict__ eids, int E)
{
    int i = blockIdx.x * blockDim.x + threadIdx.x;
    const int st = gridDim.x * blockDim.x;
    for (; i < E; i += st) {
        int pos = atomicAdd(&cur[ei[E + i]], 1);
        eids[pos] = i;
    }
}

// sat[slot] = {src_as_float, att}; padding slots (eid<0) -> {0, 0}
__global__ void permute_sat(
    const int* __restrict__ ei, const float* __restrict__ eatten,
    const int* __restrict__ eids, const int* __restrict__ offN,
    float2* __restrict__ sat, int Scap)
{
    const int S = *offN;
    int i = blockIdx.x * blockDim.x + threadIdx.x;
    const int st = gridDim.x * blockDim.x;
    for (; i < Scap; i += st) {
        if (i >= S) break;
        const int eid = eids[i];
        float2 v;
        if (eid >= 0) { v.x = __int_as_float(ei[eid]); v.y = eatten[eid]; }
        else          { v.x = __int_as_float(0);       v.y = 0.f; }
        sat[i] = v;
    }
}

// ---------------------------------------------------------------------------
// eabuild: ea = edge_attr@W_ee + b_ee, f16 half2, PAIR-INTERLEAVED layout:
//   eab2[(slot>>1)*128 + lane*2 + (slot&1)]
// ---------------------------------------------------------------------------
__global__ __launch_bounds__(256) void eabuild_staged(
    const int* __restrict__ eids, const float* __restrict__ eattr,
    const float* __restrict__ W_ee, const float* __restrict__ b_ee,
    const int* __restrict__ offN, uint32_t* __restrict__ eab2, int Scap)
{
    __shared__ int   se[256];
    __shared__ float sattr[256 * 16];
    const int t = threadIdx.x;
    const int lane = t & 63;
    const int wv = t >> 6;
    const int c = lane * 2;

    const int S = *offN;
    const int base = blockIdx.x * 256;
    const int n = min(256, S - base);
    if (n <= 0) return;

    float2 w[16];
#pragma unroll
    for (int k = 0; k < 16; ++k) w[k] = *(const float2*)&W_ee[k * 128 + c];
    const float2 bv = *(const float2*)&b_ee[c];

    if (t < n) se[t] = eids[base + t];
    __syncthreads();

    float4* sa4 = (float4*)sattr;
    const float4* ea4 = (const float4*)eattr;
    for (int i = t; i < n * 4; i += 256) {
        const int row = i >> 2, part = i & 3;
        const int eid = se[row];
        sa4[i] = (eid >= 0) ? ea4[(size_t)eid * 4 + part]
                            : make_float4(0.f, 0.f, 0.f, 0.f);
    }
    __syncthreads();

    for (int slot = wv; slot < n; slot += 4) {
        const int gs = base + slot;
        uint32_t out = 0;
        if (se[slot] >= 0) {
            const float4* sr = (const float4*)&sattr[slot * 16];
            float4 e0 = sr[0], e1 = sr[1], e2 = sr[2], e3 = sr[3];
            const float ef[16] = {e0.x, e0.y, e0.z, e0.w, e1.x, e1.y, e1.z, e1.w,
                                  e2.x, e2.y, e2.z, e2.w, e3.x, e3.y, e3.z, e3.w};
            float d0 = bv.x, d1 = bv.y;
#pragma unroll
            for (int k = 0; k < 16; ++k) {
                d0 = fmaf(ef[k], w[k].x, d0);
                d1 = fmaf(ef[k], w[k].y, d1);
            }
            __half2 hh = __floats2half2_rn(d0, d1);
            out = *reinterpret_cast<uint32_t*>(&hh);
        }
        eab2[(size_t)(gs >> 1) * 128 + lane * 2 + (gs & 1)] = out;
    }
}

// ---------------------------------------------------------------------------
// FUSED layer: agg (64 nodes -> LDS) + MLP (GEMM1+BN+ReLU+GEMM2+ReLU).
// Edge ranges are even-aligned and even-length; pair loads throughout.
// ---------------------------------------------------------------------------
__global__ __launch_bounds__(512, 4) void layer_fused(
    const float* __restrict__ h_in,
    const float2* __restrict__ sat, const uint32_t* __restrict__ eab2,
    const int* __restrict__ off,
    const float* __restrict__ W1, const float* __restrict__ b1,
    const float* __restrict__ gam, const float* __restrict__ bet,
    const float* __restrict__ mu, const float* __restrict__ var,
    const float* __restrict__ W2, const float* __restrict__ b2,
    float* __restrict__ h_out, const float* __restrict__ eps, int layer, int n)
{
    __shared__ float At[64][128];
    __shared__ float Wb[2][16][128];
    const int t = threadIdx.x;
    const int lane = t & 63;
    const int wv = t >> 6;
    const int c = lane * 2;
    const int row0 = blockIdx.x * 64;

    const float4* W14 = (const float4*)W1;
    ((float4*)&Wb[0][0][0])[t] = W14[t];

    // ---- phase A: aggregation (each wave: 8 nodes) ----
    const float sc = 1.0f + eps[layer];
    for (int r = wv; r < 64; r += 8) {
        const int v = row0 + r;
        if (v >= n) { *(float2*)&At[r][c] = make_float2(0.f, 0.f); continue; }
        const int e0 = off[v], e1 = off[v + 1];   // even-aligned, even length
        float a0 = 0.f, a1 = 0.f;
        int e = e0;
        for (; e + 8 <= e1; e += 8) {
            float4 sa[4];
#pragma unroll
            for (int j = 0; j < 4; ++j) sa[j] = *(const float4*)&sat[e + 2 * j];
            uint2 eb[4];
#pragma unroll
            for (int j = 0; j < 4; ++j)
                eb[j] = *(const uint2*)&eab2[(size_t)((e >> 1) + j) * 128 + lane * 2];
            float2 hv[8];
#pragma unroll
            for (int j = 0; j < 4; ++j) {
                hv[2 * j]     = *(const float2*)&h_in[(size_t)__float_as_int(sa[j].x) * 128 + c];
                hv[2 * j + 1] = *(const float2*)&h_in[(size_t)__float_as_int(sa[j].z) * 128 + c];
            }
#pragma unroll
            for (int j = 0; j < 4; ++j) {
                __half2 h0 = *reinterpret_cast<const __half2*>(&eb[j].x);
                a0 += fmaxf(hv[2 * j].x + __half2float(__low2half(h0)), 0.f) * sa[j].y;
                a1 += fmaxf(hv[2 * j].y + __half2float(__high2half(h0)), 0.f) * sa[j].y;
                __half2 h1 = *reinterpret_cast<const __half2*>(&eb[j].y);
                a0 += fmaxf(hv[2 * j + 1].x + __half2float(__low2half(h1)), 0.f) * sa[j].w;
                a1 += fmaxf(hv[2 * j + 1].y + __half2float(__high2half(h1)), 0.f) * sa[j].w;
            }
        }
        for (; e < e1; e += 2) {
            float4 sa = *(const float4*)&sat[e];
            uint2 eb = *(const uint2*)&eab2[(size_t)(e >> 1) * 128 + lane * 2];
            float2 h0 = *(const float2*)&h_in[(size_t)__float_as_int(sa.x) * 128 + c];
            float2 h1 = *(const float2*)&h_in[(size_t)__float_as_int(sa.z) * 128 + c];
            __half2 q0 = *reinterpret_cast<const __half2*>(&eb.x);
            a0 += fmaxf(h0.x + __half2float(__low2half(q0)), 0.f) * sa.y;
            a1 += fmaxf(h0.y + __half2float(__high2half(q0)), 0.f) * sa.y;
            __half2 q1 = *reinterpret_cast<const __half2*>(&eb.y);
            a0 += fmaxf(h1.x + __half2float(__low2half(q1)), 0.f) * sa.w;
            a1 += fmaxf(h1.y + __half2float(__high2half(q1)), 0.f) * sa.w;
        }
        const float2 hv = *(const float2*)&h_in[(size_t)v * 128 + c];
        At[r][c]     = fmaf(sc, hv.x, a0);
        At[r][c + 1] = fmaf(sc, hv.y, a1);
    }
    __syncthreads();

    // ---- phase B: GEMM1 ----
    const int tx = t & 31, ty = t >> 5;
    float acc[4][4] = {};
    for (int cc = 0; cc < 8; ++cc) {
        const int buf = cc & 1;
        float4 wnext;
        if (cc < 7) wnext = W14[(cc + 1) * 512 + t];
#pragma unroll
        for (int g = 0; g < 4; ++g) {
            float4 w4[4];
#pragma unroll
            for (int kk = 0; kk < 4; ++kk) w4[kk] = *(const float4*)&Wb[buf][g * 4 + kk][tx * 4];
#pragma unroll
            for (int r = 0; r < 4; ++r) {
                float4 a = *(const float4*)&At[ty * 4 + r][cc * 16 + g * 4];
                float ar[4] = {a.x, a.y, a.z, a.w};
#pragma unroll
                for (int kk = 0; kk < 4; ++kk) {
                    acc[r][0] = fmaf(ar[kk], w4[kk].x, acc[r][0]);
                    acc[r][1] = fmaf(ar[kk], w4[kk].y, acc[r][1]);
                    acc[r][2] = fmaf(ar[kk], w4[kk].z, acc[r][2]);
                    acc[r][3] = fmaf(ar[kk], w4[kk].w, acc[r][3]);
                }
            }
        }
        if (cc < 7) ((float4*)&Wb[buf ^ 1][0][0])[t] = wnext;
        __syncthreads();
    }

    // ---- BN + ReLU -> At, stage W2 chunk 0 ----
    const int c0 = tx * 4;
    const float4* W24 = (const float4*)W2;
    float4 w2pre = W24[t];
    {
        float b1v[4], scv[4], shv[4];
#pragma unroll
        for (int cl = 0; cl < 4; ++cl) {
            b1v[cl] = b1[c0 + cl];
            float s = gam[c0 + cl] * rsqrtf(var[c0 + cl] + 1e-5f);
            scv[cl] = s;
            shv[cl] = bet[c0 + cl] - mu[c0 + cl] * s;
        }
#pragma unroll
        for (int r = 0; r < 4; ++r) {
            float4 y;
            y.x = fmaxf(fmaf(acc[r][0] + b1v[0], scv[0], shv[0]), 0.f);
            y.y = fmaxf(fmaf(acc[r][1] + b1v[1], scv[1], shv[1]), 0.f);
            y.z = fmaxf(fmaf(acc[r][2] + b1v[2], scv[2], shv[2]), 0.f);
            y.w = fmaxf(fmaf(acc[r][3] + b1v[3], scv[3], shv[3]), 0.f);
            *(float4*)&At[ty * 4 + r][c0] = y;
            acc[r][0] = 0.f; acc[r][1] = 0.f; acc[r][2] = 0.f; acc[r][3] = 0.f;
        }
    }
    ((float4*)&Wb[0][0][0])[t] = w2pre;
    __syncthreads();

    // ---- GEMM2 ----
    for (int cc = 0; cc < 8; ++cc) {
        const int buf = cc & 1;
        float4 wnext;
        if (cc < 7) wnext = W24[(cc + 1) * 512 + t];
#pragma unroll
        for (int g = 0; g < 4; ++g) {
            float4 w4[4];
#pragma unroll
            for (int kk = 0; kk < 4; ++kk) w4[kk] = *(const float4*)&Wb[buf][g * 4 + kk][tx * 4];
#pragma unroll
            for (int r = 0; r < 4; ++r) {
                float4 a = *(const float4*)&At[ty * 4 + r][cc * 16 + g * 4];
                float ar[4] = {a.x, a.y, a.z, a.w};
#pragma unroll
                for (int kk = 0; kk < 4; ++kk) {
                    acc[r][0] = fmaf(ar[kk], w4[kk].x, acc[r][0]);
                    acc[r][1] = fmaf(ar[kk], w4[kk].y, acc[r][1]);
                    acc[r][2] = fmaf(ar[kk], w4[kk].z, acc[r][2]);
                    acc[r][3] = fmaf(ar[kk], w4[kk].w, acc[r][3]);
                }
            }
        }
        if (cc < 7) ((float4*)&Wb[buf ^ 1][0][0])[t] = wnext;
        __syncthreads();
    }

    float b2v[4];
#pragma unroll
    for (int cl = 0; cl < 4; ++cl) b2v[cl] = b2[c0 + cl];
#pragma unroll
    for (int r = 0; r < 4; ++r) {
        int row = row0 + ty * 4 + r;
        if (row < n) {
            float4 o;
            o.x = fmaxf(acc[r][0] + b2v[0], 0.f);
            o.y = fmaxf(acc[r][1] + b2v[1], 0.f);
            o.z = fmaxf(acc[r][2] + b2v[2], 0.f);
            o.w = fmaxf(acc[r][3] + b2v[3], 0.f);
            *(float4*)&h_out[(size_t)row * 128 + c0] = o;
        }
    }
}

// ---------------------------------------------------------------------------
// Encoder GEMM: h = A@W + b.
// ---------------------------------------------------------------------------
__global__ __launch_bounds__(512, 4) void gemm_enc(
    const float* __restrict__ A, const float* __restrict__ W,
    const float* __restrict__ bias, float* __restrict__ H, int n)
{
    __shared__ float At[64][128];
    __shared__ float Wb[2][16][128];
    const int t = threadIdx.x;
    const int tx = t & 31, ty = t >> 5;

    const int row0 = blockIdx.x * 64;
    const int nrows = min(64, n - row0);
    const int lim = nrows * 32;
    const float4* A4 = (const float4*)(A + (size_t)row0 * 128);
    float4* At4 = (float4*)&At[0][0];
#pragma unroll
    for (int i = 0; i < 4; ++i) {
        int idx = t + 512 * i;
        if (idx < lim) At4[idx] = A4[idx];
    }
    const float4* W4 = (const float4*)W;
    ((float4*)&Wb[0][0][0])[t] = W4[t];
    __syncthreads();

    float acc[4][4] = {};
    for (int c = 0; c < 8; ++c) {
        const int buf = c & 1;
        float4 wnext;
        if (c < 7) wnext = W4[(c + 1) * 512 + t];
#pragma unroll
        for (int g = 0; g < 4; ++g) {
            float4 w4[4];
#pragma unroll
            for (int kk = 0; kk < 4; ++kk) w4[kk] = *(const float4*)&Wb[buf][g * 4 + kk][tx * 4];
#pragma unroll
            for (int r = 0; r < 4; ++r) {
                float4 a = *(const float4*)&At[ty * 4 + r][c * 16 + g * 4];
                float ar[4] = {a.x, a.y, a.z, a.w};
#pragma unroll
                for (int kk = 0; kk < 4; ++kk) {
                    acc[r][0] = fmaf(ar[kk], w4[kk].x, acc[r][0]);
                    acc[r][1] = fmaf(ar[kk], w4[kk].y, acc[r][1]);
                    acc[r][2] = fmaf(ar[kk], w4[kk].z, acc[r][2]);
                    acc[r][3] = fmaf(ar[kk], w4[kk].w, acc[r][3]);
                }
            }
        }
        if (c < 7) ((float4*)&Wb[buf ^ 1][0][0])[t] = wnext;
        __syncthreads();
    }

    const int c0 = tx * 4;
    float bvv[4];
#pragma unroll
    for (int c = 0; c < 4; ++c) bvv[c] = bias[c0 + c];
#pragma unroll
    for (int r = 0; r < 4; ++r) {
        int row = row0 + ty * 4 + r;
        if (row < n) {
            float4 o;
            o.x = acc[r][0] + bvv[0]; o.y = acc[r][1] + bvv[1];
            o.z = acc[r][2] + bvv[2]; o.w = acc[r][3] + bvv[3];
            *(float4*)&H[(size_t)row * 128 + c0] = o;
        }
    }
}

// ---------------------------------------------------------------------------
// Last-resort fallback tier: scale_init + atomic edge kernel + gemm_mlp
// ---------------------------------------------------------------------------
__global__ void scale_init(const float* __restrict__ h, float* __restrict__ z,
                           const float* __restrict__ eps, int layer, int n4)
{
    const float s = 1.0f + eps[layer];
    int i = blockIdx.x * blockDim.x + threadIdx.x;
    const int stride = gridDim.x * blockDim.x;
    const float4* h4 = (const float4*)h;
    float4* z4 = (float4*)z;
    for (; i < n4; i += stride) {
        float4 v = h4[i];
        v.x *= s; v.y *= s; v.z *= s; v.w *= s;
        z4[i] = v;
    }
}

__global__ __launch_bounds__(256) void edge_atomic(
    const float* __restrict__ h, const int* __restrict__ ei,
    const float* __restrict__ eattr, const float* __restrict__ eatten,
    const float* __restrict__ W_ee, const float* __restrict__ b_ee,
    float* __restrict__ Z, int E)
{
    __shared__ float Wee[16][128];
    __shared__ float bee[128];
    const int t = threadIdx.x;
    const float4* We4 = (const float4*)W_ee;
    float4* Ws4 = (float4*)&Wee[0][0];
#pragma unroll
    for (int i = 0; i < 2; ++i) Ws4[t + 256 * i] = We4[t + 256 * i];
    if (t < 128) bee[t] = b_ee[t];
    __syncthreads();

    const int lane = t & 63;
    const int c = lane * 2;
    const long wid = (long)blockIdx.x * 4 + (t >> 6);
    const long nw = (long)gridDim.x * 4;
    for (long e = wid; e < E; e += nw) {
        const int src = ei[e];
        const int dst = ei[E + e];
        const float att = eatten[e];
        union { float4 v4[4]; float f[16]; } ea;
        const float4* eap = (const float4*)(eattr + e * 16);
        ea.v4[0] = eap[0]; ea.v4[1] = eap[1]; ea.v4[2] = eap[2]; ea.v4[3] = eap[3];
        float2 hv = *(const float2*)&h[(size_t)src * 128 + c];
        float e0 = bee[c], e1 = bee[c + 1];
#pragma unroll
        for (int k = 0; k < 16; ++k) {
            float2 w = *(const float2*)&Wee[k][c];
            e0 = fmaf(ea.f[k], w.x, e0);
            e1 = fmaf(ea.f[k], w.y, e1);
        }
        float m0 = fmaxf(hv.x + e0, 0.f) * att;
        float m1 = fmaxf(hv.y + e1, 0.f) * att;
        atomic_add2(&Z[(size_t)dst * 128 + c], m0, m1);
    }
}

__global__ __launch_bounds__(512, 4) void gemm_mlp(
    const float* __restrict__ Z,
    const float* __restrict__ W1, const float* __restrict__ b1,
    const float* __restrict__ gam, const float* __restrict__ bet,
    const float* __restrict__ mu, const float* __restrict__ var,
    const float* __restrict__ W2, const float* __restrict__ b2,
    float* __restrict__ H, int n)
{
    __shared__ float At[64][128];
    __shared__ float Wb[2][16][128];
    const int t = threadIdx.x;
    const int tx = t & 31, ty = t >> 5;

    const int row0 = blockIdx.x * 64;
    const int nrows = min(64, n - row0);
    const int lim = nrows * 32;
    const float4* Z4 = (const float4*)(Z + (size_t)row0 * 128);
    float4* At4 = (float4*)&At[0][0];
#pragma unroll
    for (int i = 0; i < 4; ++i) {
        int idx = t + 512 * i;
        if (idx < lim) At4[idx] = Z4[idx];
    }
    const float4* W14 = (const float4*)W1;
    ((float4*)&Wb[0][0][0])[t] = W14[t];
    __syncthreads();

    float acc[4][4] = {};
    for (int c = 0; c < 8; ++c) {
        const int buf = c & 1;
        float4 wnext;
        if (c < 7) wnext = W14[(c + 1) * 512 + t];
#pragma unroll
        for (int g = 0; g < 4; ++g) {
            float4 w4[4];
#pragma unroll
            for (int kk = 0; kk < 4; ++kk) w4[kk] = *(const float4*)&Wb[buf][g * 4 + kk][tx * 4];
#pragma unroll
            for (int r = 0; r < 4; ++r) {
                float4 a = *(const float4*)&At[ty * 4 + r][c * 16 + g * 4];
                float ar[4] = {a.x, a.y, a.z, a.w};
#pragma unroll
                for (int kk = 0; kk < 4; ++kk) {
                    acc[r][0] = fmaf(ar[kk], w4[kk].x, acc[r][0]);
                    acc[r][1] = fmaf(ar[kk], w4[kk].y, acc[r][1]);
                    acc[r][2] = fmaf(ar[kk], w4[kk].z, acc[r][2]);
                    acc[r][3] = fmaf(ar[kk], w4[kk].w, acc[r][3]);
                }
            }
        }
        if (c < 7) ((float4*)&Wb[buf ^ 1][0][0])[t] = wnext;
        __syncthreads();
    }

    const int c0 = tx * 4;
    const float4* W24 = (const float4*)W2;
    float4 w2pre = W24[t];
    {
        float b1v[4], scv[4], shv[4];
#pragma unroll
        for (int cl = 0; cl < 4; ++cl) {
            b1v[cl] = b1[c0 + cl];
            float s = gam[c0 + cl] * rsqrtf(var[c0 + cl] + 1e-5f);
            scv[cl] = s;
            shv[cl] = bet[c0 + cl] - mu[c0 + cl] * s;
        }
#pragma unroll
        for (int r = 0; r < 4; ++r) {
            float4 y;
            y.x = fmaxf(fmaf(acc[r][0] + b1v[0], scv[0], shv[0]), 0.f);
            y.y = fmaxf(fmaf(acc[r][1] + b1v[1], scv[1], shv[1]), 0.f);
            y.z = fmaxf(fmaf(acc[r][2] + b1v[2], scv[2], shv[2]), 0.f);
            y.w = fmaxf(fmaf(acc[r][3] + b1v[3], scv[3], shv[3]), 0.f);
            *(float4*)&At[ty * 4 + r][c0] = y;
            acc[r][0] = 0.f; acc[r][1] = 0.f; acc[r][2] = 0.f; acc[r][3] = 0.f;
        }
    }
    ((float4*)&Wb[0][0][0])[t] = w2pre;
    __syncthreads();

    for (int c = 0; c < 8; ++c) {
        const int buf = c & 1;
        float4 wnext;
        if (c < 7) wnext = W24[(c + 1) * 512 + t];
#pragma unroll
        for (int g = 0; g < 4; ++g) {
            float4 w4[4];
#pragma unroll
            for (int kk = 0; kk < 4; ++kk) w4[kk] = *(const float4*)&Wb[buf][g * 4 + kk][tx * 4];
#pragma unroll
            for (int r = 0; r < 4; ++r) {
                float4 a = *(const float4*)&At[ty * 4 + r][c * 16 + g * 4];
                float ar[4] = {a.x, a.y, a.z, a.w};
#pragma unroll
                for (int kk = 0; kk < 4; ++kk) {
                    acc[r][0] = fmaf(ar[kk], w4[kk].x, acc[r][0]);
                    acc[r][1] = fmaf(ar[kk], w4[kk].y, acc[r][1]);
                    acc[r][2] = fmaf(ar[kk], w4[kk].z, acc[r][2]);
                    acc[r][3] = fmaf(ar[kk], w4[kk].w, acc[r][3]);
                }
            }
        }
        if (c < 7) ((float4*)&Wb[buf ^ 1][0][0])[t] = wnext;
        __syncthreads();
    }

    float b2v[4];
#pragma unroll
    for (int cl = 0; cl < 4; ++cl) b2v[cl] = b2[c0 + cl];
#pragma unroll
    for (int r = 0; r < 4; ++r) {
        int row = row0 + ty * 4 + r;
        if (row < n) {
            float4 o;
            o.x = fmaxf(acc[r][0] + b2v[0], 0.f);
            o.y = fmaxf(acc[r][1] + b2v[1], 0.f);
            o.z = fmaxf(acc[r][2] + b2v[2], 0.f);
            o.w = fmaxf(acc[r][3] + b2v[3], 0.f);
            *(float4*)&H[(size_t)row * 128 + c0] = o;
        }
    }
}

extern "C" void kernel_launch(void* const* d_in, const int* in_sizes, int n_in,
                              void* d_out, int out_size, void* d_ws, size_t ws_size,
                              hipStream_t stream)
{
    const float* x      = (const float*)d_in[0];
    const int*   ei     = (const int*)d_in[1];
    // d_in[2] = batch (unused)
    const float* eattr  = (const float*)d_in[3];
    const float* eatten = (const float*)d_in[4];
    const float* W_enc  = (const float*)d_in[5];
    const float* b_enc  = (const float*)d_in[6];
    const float* W_ee   = (const float*)d_in[7];
    const float* b_ee   = (const float*)d_in[8];
    const float* eps    = (const float*)d_in[9];
    const float* W1     = (const float*)d_in[10];
    const float* b1     = (const float*)d_in[11];
    const float* gam    = (const float*)d_in[12];
    const float* bet    = (const float*)d_in[13];
    const float* mu     = (const float*)d_in[14];
    const float* var    = (const float*)d_in[15];
    const float* W2     = (const float*)d_in[16];
    const float* b2     = (const float*)d_in[17];

    const int N = in_sizes[0] / 128;
    const int E = in_sizes[1] / 2;
    const int L = in_sizes[9];
    const int Scap = E + N;      // max padded slots

    float* hout = (float*)d_out;   // [N,128]

    // workspace layout (single h buffer; ping-pong with d_out)
    const size_t hbytes = ((size_t)N * 128 * 4 + 255) & ~(size_t)255;
    char* p = (char*)d_ws;
    float* w0 = (float*)p;              p += hbytes;
    int* off  = (int*)p;                p += 4 * (size_t)(N + 1);
    int* cur  = (int*)p;                p += 4 * (size_t)N;
    int* cnt  = (int*)p;                p += 4 * (size_t)N;
    int* bsum = (int*)p;                p += 4 * 1024;
    int* eids = (int*)p;                p += 4 * (size_t)Scap;
    p = (char*)(((uintptr_t)p + 255) & ~(uintptr_t)255);
    float2* sat = (float2*)p;           p += 8 * (size_t)Scap;
    p = (char*)(((uintptr_t)p + 255) & ~(uintptr_t)255);
    uint32_t* eab2 = (uint32_t*)p;      p += 512 * (size_t)((Scap + 1) / 2);
    const size_t need_fused = (size_t)(p - (char*)d_ws);

    const bool use_fused = ws_size >= need_fused;
    const int tiles = (N + 63) / 64;
    const int NB = (N + 1023) / 1024;

    if (use_fused) {
        zero_cnt<<<(N + 255) / 256, 256, 0, stream>>>(cnt, N);
        hist_kernel<<<1024, 256, 0, stream>>>(ei, cnt, E);
        scan_pass1<<<NB, 256, 0, stream>>>(cnt, bsum, N);
        scan_pass2<<<1, 256, 0, stream>>>(bsum, off, NB, N);
        scan_pass3<<<NB, 256, 0, stream>>>(cnt, bsum, off, cur, N);
        fill_neg1<<<1024, 256, 0, stream>>>(eids, Scap);
        scatter_kernel<<<1024, 256, 0, stream>>>(ei, cur, eids, E);
        permute_sat<<<1024, 256, 0, stream>>>(ei, eatten, eids, off + N, sat, Scap);
        eabuild_staged<<<(Scap + 255) / 256, 256, 0, stream>>>(
            eids, eattr, W_ee, b_ee, off + N, eab2, Scap);

        // ping-pong: A/B chosen so final layer writes d_out
        float* A = (L % 2 == 1) ? w0 : hout;
        float* B = (L % 2 == 1) ? hout : w0;
        gemm_enc<<<tiles, 512, 0, stream>>>(x, W_enc, b_enc, A, N);
        for (int i = 0; i < L; ++i) {
            const float* hin = (i & 1) ? B : A;
            float* ho = (i & 1) ? A : B;
            layer_fused<<<tiles, 512, 0, stream>>>(
                hin, sat, eab2, off,
                W1 + (size_t)i * 128 * 128, b1 + i * 128,
                gam + i * 128, bet + i * 128, mu + i * 128, var + i * 128,
                W2 + (size_t)i * 128 * 128, b2 + i * 128,
                ho, eps, i, N);
        }
        return;
    }

    // fallback: h in d_out, zbuf = w0
    float* h = hout;
    float* zbuf = w0;
    gemm_enc<<<tiles, 512, 0, stream>>>(x, W_enc, b_enc, h, N);
    for (int i = 0; i < L; ++i) {
        scale_init<<<2048, 256, 0, stream>>>(h, zbuf, eps, i, N * 128 / 4);
        edge_atomic<<<2048, 256, 0, stream>>>(h, ei, eattr, eatten, W_ee, b_ee, zbuf, E);
        gemm_mlp<<<tiles, 512, 0, stream>>>(
            zbuf, W1 + (size_t)i * 128 * 128, b1 + i * 128,
            gam + i * 128, bet + i * 128, mu + i * 128, var + i * 128,
            W2 + (size_t)i * 128 * 128, b2 + i * 128,
            h, N);
    }
}

// Round 10
// 576.510 us; speedup vs baseline: 4.1107x; 1.5066x over previous
//
#include <hip/hip_runtime.h>
#include <hip/hip_fp16.h>
#include <cstdint>
#include <cstddef>

// ---------------------------------------------------------------------------
// GIN (GINEConv x3) forward, f32 in/out, f16 internal for ea/z/Y + MFMA MLP.
//   h  = x@W_enc + b_enc                                  (gemm_enc, f32)
//   CSR build (deg padded even): hist -> scan3 -> fill -> scatter ->
//     permute(sat) -> eabuild(f16 pair-interleaved) ; prepack W1/W2 -> frags
//   per layer: agg_f16 (no LDS, high occ) -> z16 ; mlp_mfma (16x16x32 f16)
// ---------------------------------------------------------------------------

typedef _Float16 f16x8 __attribute__((ext_vector_type(8)));
typedef float    f32x4 __attribute__((ext_vector_type(4)));

// ---- packed-f32x2 atomic with compile-safe fallback (fallback tier only) ---
template <class T>
__device__ inline auto add2_impl(T* p, T v, int)
    -> decltype(unsafeAtomicAdd(p, v), void()) {
    unsafeAtomicAdd(p, v);
}
template <class T>
__device__ inline void add2_impl(T* p, T v, long) {
    unsafeAtomicAdd(&p->x, v.x);
    unsafeAtomicAdd(&p->y, v.y);
}
__device__ inline void atomic_add2(float* p, float x, float y) {
    add2_impl(reinterpret_cast<float2*>(p), make_float2(x, y), 0);
}

// ---------------------------------------------------------------------------
// CSR build
// ---------------------------------------------------------------------------
__global__ void zero_cnt(int* __restrict__ cnt, int N)
{
    int i = blockIdx.x * blockDim.x + threadIdx.x;
    if (i < N) cnt[i] = 0;
}

__global__ void fill_neg1(int* __restrict__ a, int n)
{
    int i = blockIdx.x * blockDim.x + threadIdx.x;
    const int st = gridDim.x * blockDim.x;
    for (; i < n; i += st) a[i] = -1;
}

__global__ void hist_kernel(const int* __restrict__ ei, int* __restrict__ cnt, int E)
{
    int i = blockIdx.x * blockDim.x + threadIdx.x;
    const int st = gridDim.x * blockDim.x;
    for (; i < E; i += st) atomicAdd(&cnt[ei[E + i]], 1);
}

__global__ __launch_bounds__(256) void scan_pass1(
    const int* __restrict__ cnt, int* __restrict__ bsum, int N)
{
    __shared__ int part[256];
    const int t = threadIdx.x;
    const int base = blockIdx.x * 1024 + t * 4;
    int s = 0;
#pragma unroll
    for (int j = 0; j < 4; ++j) {
        int idx = base + j;
        if (idx < N) { int v = cnt[idx]; s += v + (v & 1); }
    }
    part[t] = s;
    __syncthreads();
    for (int d = 128; d > 0; d >>= 1) {
        if (t < d) part[t] += part[t + d];
        __syncthreads();
    }
    if (t == 0) bsum[blockIdx.x] = part[0];
}

__global__ __launch_bounds__(256) void scan_pass2(
    int* __restrict__ bsum, int* __restrict__ off, int NB, int N)
{
    __shared__ int sb[1024];
    const int t = threadIdx.x;
    for (int i = t; i < NB; i += 256) sb[i] = bsum[i];
    __syncthreads();
    if (t == 0) {
        int run = 0;
        for (int i = 0; i < NB; ++i) { int v = sb[i]; sb[i] = run; run += v; }
        off[N] = run;          // total padded slots S
    }
    __syncthreads();
    for (int i = t; i < NB; i += 256) bsum[i] = sb[i];
}

__global__ __launch_bounds__(256) void scan_pass3(
    const int* __restrict__ cnt, const int* __restrict__ bsum,
    int* __restrict__ off, int* __restrict__ cur, int N)
{
    __shared__ int part[256];
    const int t = threadIdx.x;
    const int base = blockIdx.x * 1024 + t * 4;
    int pv[4]; int s = 0;
#pragma unroll
    for (int j = 0; j < 4; ++j) {
        int idx = base + j;
        int v = (idx < N) ? cnt[idx] : 0;
        pv[j] = v + (v & 1);
        s += pv[j];
    }
    part[t] = s;
    __syncthreads();
    for (int d = 1; d < 256; d <<= 1) {
        int x = (t >= d) ? part[t - d] : 0;
        __syncthreads();
        part[t] += x;
        __syncthreads();
    }
    int run = bsum[blockIdx.x] + part[t] - s;
#pragma unroll
    for (int j = 0; j < 4; ++j) {
        int idx = base + j;
        if (idx < N) { off[idx] = run; cur[idx] = run; }
        run += pv[j];
    }
}

__global__ void scatter_kernel(const int* __restrict__ ei, int* __restrict__ cur,
                               int* __restrict__ eids, int E)
{
    int i = blockIdx.x * blockDim.x + threadIdx.x;
    const int st = gridDim.x * blockDim.x;
    for (; i < E; i += st) {
        int pos = atomicAdd(&cur[ei[E + i]], 1);
        eids[pos] = i;
    }
}

__global__ void permute_sat(
    const int* __restrict__ ei, const float* __restrict__ eatten,
    const int* __restrict__ eids, const int* __restrict__ offN,
    float2* __restrict__ sat, int Scap)
{
    const int S = *offN;
    int i = blockIdx.x * blockDim.x + threadIdx.x;
    const int st = gridDim.x * blockDim.x;
    for (; i < Scap; i += st) {
        if (i >= S) break;
        const int eid = eids[i];
        float2 v;
        if (eid >= 0) { v.x = __int_as_float(ei[eid]); v.y = eatten[eid]; }
        else          { v.x = __int_as_float(0);       v.y = 0.f; }
        sat[i] = v;
    }
}

// ---------------------------------------------------------------------------
// eabuild: ea = edge_attr@W_ee + b_ee, f16 half2, pair-interleaved:
//   eab2[(slot>>1)*128 + lane*2 + (slot&1)]
// ---------------------------------------------------------------------------
__global__ __launch_bounds__(256) void eabuild_staged(
    const int* __restrict__ eids, const float* __restrict__ eattr,
    const float* __restrict__ W_ee, const float* __restrict__ b_ee,
    const int* __restrict__ offN, uint32_t* __restrict__ eab2, int Scap)
{
    __shared__ int   se[256];
    __shared__ float sattr[256 * 16];
    const int t = threadIdx.x;
    const int lane = t & 63;
    const int wv = t >> 6;
    const int c = lane * 2;

    const int S = *offN;
    const int base = blockIdx.x * 256;
    const int n = min(256, S - base);
    if (n <= 0) return;

    float2 w[16];
#pragma unroll
    for (int k = 0; k < 16; ++k) w[k] = *(const float2*)&W_ee[k * 128 + c];
    const float2 bv = *(const float2*)&b_ee[c];

    if (t < n) se[t] = eids[base + t];
    __syncthreads();

    float4* sa4 = (float4*)sattr;
    const float4* ea4 = (const float4*)eattr;
    for (int i = t; i < n * 4; i += 256) {
        const int row = i >> 2, part = i & 3;
        const int eid = se[row];
        sa4[i] = (eid >= 0) ? ea4[(size_t)eid * 4 + part]
                            : make_float4(0.f, 0.f, 0.f, 0.f);
    }
    __syncthreads();

    for (int slot = wv; slot < n; slot += 4) {
        const int gs = base + slot;
        uint32_t out = 0;
        if (se[slot] >= 0) {
            const float4* sr = (const float4*)&sattr[slot * 16];
            float4 e0 = sr[0], e1 = sr[1], e2 = sr[2], e3 = sr[3];
            const float ef[16] = {e0.x, e0.y, e0.z, e0.w, e1.x, e1.y, e1.z, e1.w,
                                  e2.x, e2.y, e2.z, e2.w, e3.x, e3.y, e3.z, e3.w};
            float d0 = bv.x, d1 = bv.y;
#pragma unroll
            for (int k = 0; k < 16; ++k) {
                d0 = fmaf(ef[k], w[k].x, d0);
                d1 = fmaf(ef[k], w[k].y, d1);
            }
            __half2 hh = __floats2half2_rn(d0, d1);
            out = *reinterpret_cast<uint32_t*>(&hh);
        }
        eab2[(size_t)(gs >> 1) * 128 + lane * 2 + (gs & 1)] = out;
    }
}

// ---------------------------------------------------------------------------
// prepack W1/W2 into MFMA B-fragment order (f16).
// frag f = kb*8+tc; element: k = kb*32+(lane>>4)*8+i, col = tc*16+(lane&15).
// Wpk[((lm*32)+f)*512 + lane*8 + i], lm in [0,2L): W1 layers then W2 layers.
// ---------------------------------------------------------------------------
__global__ void prepack_w(const float* __restrict__ W1, const float* __restrict__ W2,
                          _Float16* __restrict__ Wpk, int L)
{
    int tid = blockIdx.x * blockDim.x + threadIdx.x;
    const int total = 2 * L * 32 * 64;
    if (tid >= total) return;
    const int lane = tid & 63;
    const int f = (tid >> 6) & 31;
    const int lm = tid >> 11;
    const int kb = f >> 3, tc = f & 7;
    const float* src = (lm < L) ? (W1 + (size_t)lm * 16384)
                                : (W2 + (size_t)(lm - L) * 16384);
    _Float16* dst = Wpk + ((size_t)lm * 32 + f) * 512 + lane * 8;
#pragma unroll
    for (int i = 0; i < 8; ++i) {
        const int k = kb * 32 + (lane >> 4) * 8 + i;
        const int col = tc * 16 + (lane & 15);
        dst[i] = (_Float16)src[k * 128 + col];
    }
}

// ---------------------------------------------------------------------------
// Aggregation (standalone, no LDS): one wave per node, lane owns 2 cols.
// Pair-packed sat/eab2 loads; writes z16 (f16).
// ---------------------------------------------------------------------------
__global__ __launch_bounds__(256) void agg_f16(
    const float* __restrict__ h, const float2* __restrict__ sat,
    const uint32_t* __restrict__ eab2, const int* __restrict__ off,
    __half* __restrict__ z16, const float* __restrict__ eps, int layer, int N)
{
    const int t = threadIdx.x;
    const int v = blockIdx.x * 4 + (t >> 6);
    if (v >= N) return;
    const int lane = t & 63;
    const int c = lane * 2;

    const int e0 = off[v], e1 = off[v + 1];   // even-aligned, even length
    float a0 = 0.f, a1 = 0.f;
    int e = e0;
    for (; e + 8 <= e1; e += 8) {
        float4 sa[4];
#pragma unroll
        for (int j = 0; j < 4; ++j) sa[j] = *(const float4*)&sat[e + 2 * j];
        uint2 eb[4];
#pragma unroll
        for (int j = 0; j < 4; ++j)
            eb[j] = *(const uint2*)&eab2[(size_t)((e >> 1) + j) * 128 + lane * 2];
        float2 hv[8];
#pragma unroll
        for (int j = 0; j < 4; ++j) {
            hv[2 * j]     = *(const float2*)&h[(size_t)__float_as_int(sa[j].x) * 128 + c];
            hv[2 * j + 1] = *(const float2*)&h[(size_t)__float_as_int(sa[j].z) * 128 + c];
        }
#pragma unroll
        for (int j = 0; j < 4; ++j) {
            __half2 h0 = *reinterpret_cast<const __half2*>(&eb[j].x);
            a0 += fmaxf(hv[2 * j].x + __half2float(__low2half(h0)), 0.f) * sa[j].y;
            a1 += fmaxf(hv[2 * j].y + __half2float(__high2half(h0)), 0.f) * sa[j].y;
            __half2 h1 = *reinterpret_cast<const __half2*>(&eb[j].y);
            a0 += fmaxf(hv[2 * j + 1].x + __half2float(__low2half(h1)), 0.f) * sa[j].w;
            a1 += fmaxf(hv[2 * j + 1].y + __half2float(__high2half(h1)), 0.f) * sa[j].w;
        }
    }
    for (; e < e1; e += 2) {
        float4 sa = *(const float4*)&sat[e];
        uint2 eb = *(const uint2*)&eab2[(size_t)(e >> 1) * 128 + lane * 2];
        float2 h0 = *(const float2*)&h[(size_t)__float_as_int(sa.x) * 128 + c];
        float2 h1 = *(const float2*)&h[(size_t)__float_as_int(sa.z) * 128 + c];
        __half2 q0 = *reinterpret_cast<const __half2*>(&eb.x);
        a0 += fmaxf(h0.x + __half2float(__low2half(q0)), 0.f) * sa.y;
        a1 += fmaxf(h0.y + __half2float(__high2half(q0)), 0.f) * sa.y;
        __half2 q1 = *reinterpret_cast<const __half2*>(&eb.y);
        a0 += fmaxf(h1.x + __half2float(__low2half(q1)), 0.f) * sa.w;
        a1 += fmaxf(h1.y + __half2float(__high2half(q1)), 0.f) * sa.w;
    }

    const float sc = 1.0f + eps[layer];
    const float2 hv = *(const float2*)&h[(size_t)v * 128 + c];
    __half2 hh = __floats2half2_rn(fmaf(sc, hv.x, a0), fmaf(sc, hv.y, a1));
    *reinterpret_cast<__half2*>(&z16[(size_t)v * 128 + c]) = hh;
}

// ---------------------------------------------------------------------------
// MFMA MLP: H = relu( relu(BN(z16@W1+b1)) @ W2 + b2 ).
// 256 thr = 4 waves; wave w owns tile-row w (16 rows); 8 tile-cols each.
// A layout: row=lane&15, k=(lane>>4)*8+i.  C/D: col=lane&15, row=(lane>>4)*4+reg.
// ---------------------------------------------------------------------------
__global__ __launch_bounds__(256) void mlp_mfma(
    const __half* __restrict__ z16h,
    const _Float16* __restrict__ W1pk, const float* __restrict__ b1,
    const float* __restrict__ gam, const float* __restrict__ bet,
    const float* __restrict__ mu, const float* __restrict__ var,
    const _Float16* __restrict__ W2pk, const float* __restrict__ b2,
    float* __restrict__ H, int n)
{
    __shared__ _Float16 Yt[64][136];   // padded: stride 272B -> 2-way banks
    const _Float16* z16 = reinterpret_cast<const _Float16*>(z16h);
    const int t = threadIdx.x;
    const int lane = t & 63;
    const int w = t >> 6;              // wave = tile-row index
    const int row0 = blockIdx.x * 64;
    const int lr = lane & 15;
    const int lg = lane >> 4;

    // ---- GEMM1: z @ W1 ----
    f32x4 acc[8];
#pragma unroll
    for (int tc = 0; tc < 8; ++tc) acc[tc] = (f32x4){0.f, 0.f, 0.f, 0.f};
    const int arow = min(row0 + w * 16 + lr, n - 1);   // clamp: results unused OOB
#pragma unroll
    for (int kb = 0; kb < 4; ++kb) {
        f16x8 a = *(const f16x8*)&z16[(size_t)arow * 128 + kb * 32 + lg * 8];
#pragma unroll
        for (int tc = 0; tc < 8; ++tc) {
            f16x8 b = *(const f16x8*)&W1pk[((kb * 8 + tc) * 64 + lane) * 8];
            acc[tc] = __builtin_amdgcn_mfma_f32_16x16x32_f16(a, b, acc[tc], 0, 0, 0);
        }
    }
    // BN + ReLU -> Yt (f16)
#pragma unroll
    for (int tc = 0; tc < 8; ++tc) {
        const int col = tc * 16 + lr;
        const float s  = gam[col] * rsqrtf(var[col] + 1e-5f);
        const float sh = bet[col] - mu[col] * s;
        const float bb = b1[col];
#pragma unroll
        for (int j = 0; j < 4; ++j) {
            float y = fmaxf(fmaf(acc[tc][j] + bb, s, sh), 0.f);
            Yt[w * 16 + lg * 4 + j][col] = (_Float16)y;
        }
    }
    __syncthreads();

    // ---- GEMM2: Y @ W2 ----
#pragma unroll
    for (int tc = 0; tc < 8; ++tc) acc[tc] = (f32x4){0.f, 0.f, 0.f, 0.f};
#pragma unroll
    for (int kb = 0; kb < 4; ++kb) {
        f16x8 a = *(const f16x8*)&Yt[w * 16 + lr][kb * 32 + lg * 8];
#pragma unroll
        for (int tc = 0; tc < 8; ++tc) {
            f16x8 b = *(const f16x8*)&W2pk[((kb * 8 + tc) * 64 + lane) * 8];
            acc[tc] = __builtin_amdgcn_mfma_f32_16x16x32_f16(a, b, acc[tc], 0, 0, 0);
        }
    }
#pragma unroll
    for (int tc = 0; tc < 8; ++tc) {
        const int col = tc * 16 + lr;
        const float bb = b2[col];
#pragma unroll
        for (int j = 0; j < 4; ++j) {
            const int row = row0 + w * 16 + lg * 4 + j;
            if (row < n)
                H[(size_t)row * 128 + col] = fmaxf(acc[tc][j] + bb, 0.f);
        }
    }
}

// ---------------------------------------------------------------------------
// Encoder GEMM: h = A@W + b (f32).
// ---------------------------------------------------------------------------
__global__ __launch_bounds__(512, 4) void gemm_enc(
    const float* __restrict__ A, const float* __restrict__ W,
    const float* __restrict__ bias, float* __restrict__ H, int n)
{
    __shared__ float At[64][128];
    __shared__ float Wb[2][16][128];
    const int t = threadIdx.x;
    const int tx = t & 31, ty = t >> 5;

    const int row0 = blockIdx.x * 64;
    const int nrows = min(64, n - row0);
    const int lim = nrows * 32;
    const float4* A4 = (const float4*)(A + (size_t)row0 * 128);
    float4* At4 = (float4*)&At[0][0];
#pragma unroll
    for (int i = 0; i < 4; ++i) {
        int idx = t + 512 * i;
        if (idx < lim) At4[idx] = A4[idx];
    }
    const float4* W4 = (const float4*)W;
    ((float4*)&Wb[0][0][0])[t] = W4[t];
    __syncthreads();

    float acc[4][4] = {};
    for (int c = 0; c < 8; ++c) {
        const int buf = c & 1;
        float4 wnext;
        if (c < 7) wnext = W4[(c + 1) * 512 + t];
#pragma unroll
        for (int g = 0; g < 4; ++g) {
            float4 w4[4];
#pragma unroll
            for (int kk = 0; kk < 4; ++kk) w4[kk] = *(const float4*)&Wb[buf][g * 4 + kk][tx * 4];
#pragma unroll
            for (int r = 0; r < 4; ++r) {
                float4 a = *(const float4*)&At[ty * 4 + r][c * 16 + g * 4];
                float ar[4] = {a.x, a.y, a.z, a.w};
#pragma unroll
                for (int kk = 0; kk < 4; ++kk) {
                    acc[r][0] = fmaf(ar[kk], w4[kk].x, acc[r][0]);
                    acc[r][1] = fmaf(ar[kk], w4[kk].y, acc[r][1]);
                    acc[r][2] = fmaf(ar[kk], w4[kk].z, acc[r][2]);
                    acc[r][3] = fmaf(ar[kk], w4[kk].w, acc[r][3]);
                }
            }
        }
        if (c < 7) ((float4*)&Wb[buf ^ 1][0][0])[t] = wnext;
        __syncthreads();
    }

    const int c0 = tx * 4;
    float bvv[4];
#pragma unroll
    for (int c = 0; c < 4; ++c) bvv[c] = bias[c0 + c];
#pragma unroll
    for (int r = 0; r < 4; ++r) {
        int row = row0 + ty * 4 + r;
        if (row < n) {
            float4 o;
            o.x = acc[r][0] + bvv[0]; o.y = acc[r][1] + bvv[1];
            o.z = acc[r][2] + bvv[2]; o.w = acc[r][3] + bvv[3];
            *(float4*)&H[(size_t)row * 128 + c0] = o;
        }
    }
}

// ---------------------------------------------------------------------------
// Last-resort fallback tier (f32 end-to-end): scale_init + atomic + gemm_mlp
// ---------------------------------------------------------------------------
__global__ void scale_init(const float* __restrict__ h, float* __restrict__ z,
                           const float* __restrict__ eps, int layer, int n4)
{
    const float s = 1.0f + eps[layer];
    int i = blockIdx.x * blockDim.x + threadIdx.x;
    const int stride = gridDim.x * blockDim.x;
    const float4* h4 = (const float4*)h;
    float4* z4 = (float4*)z;
    for (; i < n4; i += stride) {
        float4 v = h4[i];
        v.x *= s; v.y *= s; v.z *= s; v.w *= s;
        z4[i] = v;
    }
}

__global__ __launch_bounds__(256) void edge_atomic(
    const float* __restrict__ h, const int* __restrict__ ei,
    const float* __restrict__ eattr, const float* __restrict__ eatten,
    const float* __restrict__ W_ee, const float* __restrict__ b_ee,
    float* __restrict__ Z, int E)
{
    __shared__ float Wee[16][128];
    __shared__ float bee[128];
    const int t = threadIdx.x;
    const float4* We4 = (const float4*)W_ee;
    float4* Ws4 = (float4*)&Wee[0][0];
#pragma unroll
    for (int i = 0; i < 2; ++i) Ws4[t + 256 * i] = We4[t + 256 * i];
    if (t < 128) bee[t] = b_ee[t];
    __syncthreads();

    const int lane = t & 63;
    const int c = lane * 2;
    const long wid = (long)blockIdx.x * 4 + (t >> 6);
    const long nw = (long)gridDim.x * 4;
    for (long e = wid; e < E; e += nw) {
        const int src = ei[e];
        const int dst = ei[E + e];
        const float att = eatten[e];
        union { float4 v4[4]; float f[16]; } ea;
        const float4* eap = (const float4*)(eattr + e * 16);
        ea.v4[0] = eap[0]; ea.v4[1] = eap[1]; ea.v4[2] = eap[2]; ea.v4[3] = eap[3];
        float2 hv = *(const float2*)&h[(size_t)src * 128 + c];
        float e0 = bee[c], e1 = bee[c + 1];
#pragma unroll
        for (int k = 0; k < 16; ++k) {
            float2 w = *(const float2*)&Wee[k][c];
            e0 = fmaf(ea.f[k], w.x, e0);
            e1 = fmaf(ea.f[k], w.y, e1);
        }
        float m0 = fmaxf(hv.x + e0, 0.f) * att;
        float m1 = fmaxf(hv.y + e1, 0.f) * att;
        atomic_add2(&Z[(size_t)dst * 128 + c], m0, m1);
    }
}

__global__ __launch_bounds__(512, 4) void gemm_mlp(
    const float* __restrict__ Z,
    const float* __restrict__ W1, const float* __restrict__ b1,
    const float* __restrict__ gam, const float* __restrict__ bet,
    const float* __restrict__ mu, const float* __restrict__ var,
    const float* __restrict__ W2, const float* __restrict__ b2,
    float* __restrict__ H, int n)
{
    __shared__ float At[64][128];
    __shared__ float Wb[2][16][128];
    const int t = threadIdx.x;
    const int tx = t & 31, ty = t >> 5;

    const int row0 = blockIdx.x * 64;
    const int nrows = min(64, n - row0);
    const int lim = nrows * 32;
    const float4* Z4 = (const float4*)(Z + (size_t)row0 * 128);
    float4* At4 = (float4*)&At[0][0];
#pragma unroll
    for (int i = 0; i < 4; ++i) {
        int idx = t + 512 * i;
        if (idx < lim) At4[idx] = Z4[idx];
    }
    const float4* W14 = (const float4*)W1;
    ((float4*)&Wb[0][0][0])[t] = W14[t];
    __syncthreads();

    float acc[4][4] = {};
    for (int c = 0; c < 8; ++c) {
        const int buf = c & 1;
        float4 wnext;
        if (c < 7) wnext = W14[(c + 1) * 512 + t];
#pragma unroll
        for (int g = 0; g < 4; ++g) {
            float4 w4[4];
#pragma unroll
            for (int kk = 0; kk < 4; ++kk) w4[kk] = *(const float4*)&Wb[buf][g * 4 + kk][tx * 4];
#pragma unroll
            for (int r = 0; r < 4; ++r) {
                float4 a = *(const float4*)&At[ty * 4 + r][c * 16 + g * 4];
                float ar[4] = {a.x, a.y, a.z, a.w};
#pragma unroll
                for (int kk = 0; kk < 4; ++kk) {
                    acc[r][0] = fmaf(ar[kk], w4[kk].x, acc[r][0]);
                    acc[r][1] = fmaf(ar[kk], w4[kk].y, acc[r][1]);
                    acc[r][2] = fmaf(ar[kk], w4[kk].z, acc[r][2]);
                    acc[r][3] = fmaf(ar[kk], w4[kk].w, acc[r][3]);
                }
            }
        }
        if (c < 7) ((float4*)&Wb[buf ^ 1][0][0])[t] = wnext;
        __syncthreads();
    }

    const int c0 = tx * 4;
    const float4* W24 = (const float4*)W2;
    float4 w2pre = W24[t];
    {
        float b1v[4], scv[4], shv[4];
#pragma unroll
        for (int cl = 0; cl < 4; ++cl) {
            b1v[cl] = b1[c0 + cl];
            float s = gam[c0 + cl] * rsqrtf(var[c0 + cl] + 1e-5f);
            scv[cl] = s;
            shv[cl] = bet[c0 + cl] - mu[c0 + cl] * s;
        }
#pragma unroll
        for (int r = 0; r < 4; ++r) {
            float4 y;
            y.x = fmaxf(fmaf(acc[r][0] + b1v[0], scv[0], shv[0]), 0.f);
            y.y = fmaxf(fmaf(acc[r][1] + b1v[1], scv[1], shv[1]), 0.f);
            y.z = fmaxf(fmaf(acc[r][2] + b1v[2], scv[2], shv[2]), 0.f);
            y.w = fmaxf(fmaf(acc[r][3] + b1v[3], scv[3], shv[3]), 0.f);
            *(float4*)&At[ty * 4 + r][c0] = y;
            acc[r][0] = 0.f; acc[r][1] = 0.f; acc[r][2] = 0.f; acc[r][3] = 0.f;
        }
    }
    ((float4*)&Wb[0][0][0])[t] = w2pre;
    __syncthreads();

    for (int c = 0; c < 8; ++c) {
        const int buf = c & 1;
        float4 wnext;
        if (c < 7) wnext = W24[(c + 1) * 512 + t];
#pragma unroll
        for (int g = 0; g < 4; ++g) {
            float4 w4[4];
#pragma unroll
            for (int kk = 0; kk < 4; ++kk) w4[kk] = *(const float4*)&Wb[buf][g * 4 + kk][tx * 4];
#pragma unroll
            for (int r = 0; r < 4; ++r) {
                float4 a = *(const float4*)&At[ty * 4 + r][c * 16 + g * 4];
                float ar[4] = {a.x, a.y, a.z, a.w};
#pragma unroll
                for (int kk = 0; kk < 4; ++kk) {
                    acc[r][0] = fmaf(ar[kk], w4[kk].x, acc[r][0]);
                    acc[r][1] = fmaf(ar[kk], w4[kk].y, acc[r][1]);
                    acc[r][2] = fmaf(ar[kk], w4[kk].z, acc[r][2]);
                    acc[r][3] = fmaf(ar[kk], w4[kk].w, acc[r][3]);
                }
            }
        }
        if (c < 7) ((float4*)&Wb[buf ^ 1][0][0])[t] = wnext;
        __syncthreads();
    }

    float b2v[4];
#pragma unroll
    for (int cl = 0; cl < 4; ++cl) b2v[cl] = b2[c0 + cl];
#pragma unroll
    for (int r = 0; r < 4; ++r) {
        int row = row0 + ty * 4 + r;
        if (row < n) {
            float4 o;
            o.x = fmaxf(acc[r][0] + b2v[0], 0.f);
            o.y = fmaxf(acc[r][1] + b2v[1], 0.f);
            o.z = fmaxf(acc[r][2] + b2v[2], 0.f);
            o.w = fmaxf(acc[r][3] + b2v[3], 0.f);
            *(float4*)&H[(size_t)row * 128 + c0] = o;
        }
    }
}

extern "C" void kernel_launch(void* const* d_in, const int* in_sizes, int n_in,
                              void* d_out, int out_size, void* d_ws, size_t ws_size,
                              hipStream_t stream)
{
    const float* x      = (const float*)d_in[0];
    const int*   ei     = (const int*)d_in[1];
    // d_in[2] = batch (unused)
    const float* eattr  = (const float*)d_in[3];
    const float* eatten = (const float*)d_in[4];
    const float* W_enc  = (const float*)d_in[5];
    const float* b_enc  = (const float*)d_in[6];
    const float* W_ee   = (const float*)d_in[7];
    const float* b_ee   = (const float*)d_in[8];
    const float* eps    = (const float*)d_in[9];
    const float* W1     = (const float*)d_in[10];
    const float* b1     = (const float*)d_in[11];
    const float* gam    = (const float*)d_in[12];
    const float* bet    = (const float*)d_in[13];
    const float* mu     = (const float*)d_in[14];
    const float* var    = (const float*)d_in[15];
    const float* W2     = (const float*)d_in[16];
    const float* b2     = (const float*)d_in[17];

    const int N = in_sizes[0] / 128;
    const int E = in_sizes[1] / 2;
    const int L = in_sizes[9];
    const int Scap = E + N;      // max padded slots

    float* h = (float*)d_out;    // [N,128] f32; lives in d_out throughout

    // workspace layout (main path)
    char* p = (char*)d_ws;
    __half* z16 = (__half*)p;           p += ((size_t)N * 128 * 2 + 255) & ~(size_t)255;
    int* off  = (int*)p;                p += 4 * (size_t)(N + 1);
    int* cur  = (int*)p;                p += 4 * (size_t)N;
    int* cnt  = (int*)p;                p += 4 * (size_t)N;
    int* bsum = (int*)p;                p += 4 * 1024;
    int* eids = (int*)p;                p += 4 * (size_t)Scap;
    p = (char*)(((uintptr_t)p + 255) & ~(uintptr_t)255);
    float2* sat = (float2*)p;           p += 8 * (size_t)Scap;
    p = (char*)(((uintptr_t)p + 255) & ~(uintptr_t)255);
    uint32_t* eab2 = (uint32_t*)p;      p += 512 * (size_t)((Scap + 1) / 2);
    p = (char*)(((uintptr_t)p + 255) & ~(uintptr_t)255);
    _Float16* Wpk = (_Float16*)p;       p += 2 * (size_t)L * 32 * 512 * 2;
    const size_t need_main = (size_t)(p - (char*)d_ws);

    const bool use_main = ws_size >= need_main;
    const int tiles = (N + 63) / 64;
    const int NB = (N + 1023) / 1024;

    if (use_main) {
        zero_cnt<<<(N + 255) / 256, 256, 0, stream>>>(cnt, N);
        hist_kernel<<<1024, 256, 0, stream>>>(ei, cnt, E);
        scan_pass1<<<NB, 256, 0, stream>>>(cnt, bsum, N);
        scan_pass2<<<1, 256, 0, stream>>>(bsum, off, NB, N);
        scan_pass3<<<NB, 256, 0, stream>>>(cnt, bsum, off, cur, N);
        fill_neg1<<<1024, 256, 0, stream>>>(eids, Scap);
        scatter_kernel<<<1024, 256, 0, stream>>>(ei, cur, eids, E);
        permute_sat<<<1024, 256, 0, stream>>>(ei, eatten, eids, off + N, sat, Scap);
        eabuild_staged<<<(Scap + 255) / 256, 256, 0, stream>>>(
            eids, eattr, W_ee, b_ee, off + N, eab2, Scap);
        prepack_w<<<(2 * L * 32 * 64 + 255) / 256, 256, 0, stream>>>(W1, W2, Wpk, L);

        gemm_enc<<<tiles, 512, 0, stream>>>(x, W_enc, b_enc, h, N);
        for (int i = 0; i < L; ++i) {
            agg_f16<<<(N + 3) / 4, 256, 0, stream>>>(
                h, sat, eab2, off, z16, eps, i, N);
            mlp_mfma<<<tiles, 256, 0, stream>>>(
                z16,
                Wpk + (size_t)i * 32 * 512, b1 + i * 128,
                gam + i * 128, bet + i * 128, mu + i * 128, var + i * 128,
                Wpk + (size_t)(L + i) * 32 * 512, b2 + i * 128,
                h, N);
        }
        return;
    }

    // fallback: f32 atomic tier (zbuf at ws start)
    float* zbuf = (float*)d_ws;
    gemm_enc<<<tiles, 512, 0, stream>>>(x, W_enc, b_enc, h, N);
    for (int i = 0; i < L; ++i) {
        scale_init<<<2048, 256, 0, stream>>>(h, zbuf, eps, i, N * 128 / 4);
        edge_atomic<<<2048, 256, 0, stream>>>(h, ei, eattr, eatten, W_ee, b_ee, zbuf, E);
        gemm_mlp<<<tiles, 512, 0, stream>>>(
            zbuf, W1 + (size_t)i * 128 * 128, b1 + i * 128,
            gam + i * 128, bet + i * 128, mu + i * 128, var + i * 128,
            W2 + (size_t)i * 128 * 128, b2 + i * 128,
            h, N);
    }
}

// Round 11
// 480.818 us; speedup vs baseline: 4.9287x; 1.1990x over previous
//
#include <hip/hip_runtime.h>
#include <hip/hip_fp16.h>
#include <cstdint>
#include <cstddef>

// ---------------------------------------------------------------------------
// GIN (GINEConv x3) forward. f32 in/out; internal h/z/ea/Y in f16; MFMA GEMMs.
//   x16 = f16(x)            (cvt, into z16 scratch)
//   h16 = x16@W_enc + b     (enc_mfma)
//   CSR (deg padded even) + sat + eab2(f16 pair-interleaved) + Wpk prepack
//   per layer: agg_f16(h16 gather) -> z16 ; mlp_mfma -> h16 (last: f32 d_out)
// ---------------------------------------------------------------------------

typedef _Float16 f16x8 __attribute__((ext_vector_type(8)));
typedef float    f32x4 __attribute__((ext_vector_type(4)));

// ---- packed-f32x2 atomic with compile-safe fallback (fallback tier only) ---
template <class T>
__device__ inline auto add2_impl(T* p, T v, int)
    -> decltype(unsafeAtomicAdd(p, v), void()) {
    unsafeAtomicAdd(p, v);
}
template <class T>
__device__ inline void add2_impl(T* p, T v, long) {
    unsafeAtomicAdd(&p->x, v.x);
    unsafeAtomicAdd(&p->y, v.y);
}
__device__ inline void atomic_add2(float* p, float x, float y) {
    add2_impl(reinterpret_cast<float2*>(p), make_float2(x, y), 0);
}

// ---------------------------------------------------------------------------
// CSR build
// ---------------------------------------------------------------------------
__global__ void zero_cnt(int* __restrict__ cnt, int N)
{
    int i = blockIdx.x * blockDim.x + threadIdx.x;
    if (i < N) cnt[i] = 0;
}

__global__ void fill_neg1(int* __restrict__ a, int n)
{
    int i = blockIdx.x * blockDim.x + threadIdx.x;
    const int st = gridDim.x * blockDim.x;
    for (; i < n; i += st) a[i] = -1;
}

__global__ void hist_kernel(const int* __restrict__ ei, int* __restrict__ cnt, int E)
{
    int i = blockIdx.x * blockDim.x + threadIdx.x;
    const int st = gridDim.x * blockDim.x;
    for (; i < E; i += st) atomicAdd(&cnt[ei[E + i]], 1);
}

__global__ __launch_bounds__(256) void scan_pass1(
    const int* __restrict__ cnt, int* __restrict__ bsum, int N)
{
    __shared__ int part[256];
    const int t = threadIdx.x;
    const int base = blockIdx.x * 1024 + t * 4;
    int s = 0;
#pragma unroll
    for (int j = 0; j < 4; ++j) {
        int idx = base + j;
        if (idx < N) { int v = cnt[idx]; s += v + (v & 1); }
    }
    part[t] = s;
    __syncthreads();
    for (int d = 128; d > 0; d >>= 1) {
        if (t < d) part[t] += part[t + d];
        __syncthreads();
    }
    if (t == 0) bsum[blockIdx.x] = part[0];
}

__global__ __launch_bounds__(256) void scan_pass2(
    int* __restrict__ bsum, int* __restrict__ off, int NB, int N)
{
    __shared__ int sb[1024];
    const int t = threadIdx.x;
    for (int i = t; i < NB; i += 256) sb[i] = bsum[i];
    __syncthreads();
    if (t == 0) {
        int run = 0;
        for (int i = 0; i < NB; ++i) { int v = sb[i]; sb[i] = run; run += v; }
        off[N] = run;          // total padded slots S
    }
    __syncthreads();
    for (int i = t; i < NB; i += 256) bsum[i] = sb[i];
}

__global__ __launch_bounds__(256) void scan_pass3(
    const int* __restrict__ cnt, const int* __restrict__ bsum,
    int* __restrict__ off, int* __restrict__ cur, int N)
{
    __shared__ int part[256];
    const int t = threadIdx.x;
    const int base = blockIdx.x * 1024 + t * 4;
    int pv[4]; int s = 0;
#pragma unroll
    for (int j = 0; j < 4; ++j) {
        int idx = base + j;
        int v = (idx < N) ? cnt[idx] : 0;
        pv[j] = v + (v & 1);
        s += pv[j];
    }
    part[t] = s;
    __syncthreads();
    for (int d = 1; d < 256; d <<= 1) {
        int x = (t >= d) ? part[t - d] : 0;
        __syncthreads();
        part[t] += x;
        __syncthreads();
    }
    int run = bsum[blockIdx.x] + part[t] - s;
#pragma unroll
    for (int j = 0; j < 4; ++j) {
        int idx = base + j;
        if (idx < N) { off[idx] = run; cur[idx] = run; }
        run += pv[j];
    }
}

__global__ void scatter_kernel(const int* __restrict__ ei, int* __restrict__ cur,
                               int* __restrict__ eids, int E)
{
    int i = blockIdx.x * blockDim.x + threadIdx.x;
    const int st = gridDim.x * blockDim.x;
    for (; i < E; i += st) {
        int pos = atomicAdd(&cur[ei[E + i]], 1);
        eids[pos] = i;
    }
}

__global__ void permute_sat(
    const int* __restrict__ ei, const float* __restrict__ eatten,
    const int* __restrict__ eids, const int* __restrict__ offN,
    float2* __restrict__ sat, int Scap)
{
    const int S = *offN;
    int i = blockIdx.x * blockDim.x + threadIdx.x;
    const int st = gridDim.x * blockDim.x;
    for (; i < Scap; i += st) {
        if (i >= S) break;
        const int eid = eids[i];
        float2 v;
        if (eid >= 0) { v.x = __int_as_float(ei[eid]); v.y = eatten[eid]; }
        else          { v.x = __int_as_float(0);       v.y = 0.f; }
        sat[i] = v;
    }
}

// ---------------------------------------------------------------------------
// eabuild: ea = edge_attr@W_ee + b_ee, f16 half2, pair-interleaved:
//   eab2[(slot>>1)*128 + lane*2 + (slot&1)]
// ---------------------------------------------------------------------------
__global__ __launch_bounds__(256) void eabuild_staged(
    const int* __restrict__ eids, const float* __restrict__ eattr,
    const float* __restrict__ W_ee, const float* __restrict__ b_ee,
    const int* __restrict__ offN, uint32_t* __restrict__ eab2, int Scap)
{
    __shared__ int   se[256];
    __shared__ float sattr[256 * 16];
    const int t = threadIdx.x;
    const int lane = t & 63;
    const int wv = t >> 6;
    const int c = lane * 2;

    const int S = *offN;
    const int base = blockIdx.x * 256;
    const int n = min(256, S - base);
    if (n <= 0) return;

    float2 w[16];
#pragma unroll
    for (int k = 0; k < 16; ++k) w[k] = *(const float2*)&W_ee[k * 128 + c];
    const float2 bv = *(const float2*)&b_ee[c];

    if (t < n) se[t] = eids[base + t];
    __syncthreads();

    float4* sa4 = (float4*)sattr;
    const float4* ea4 = (const float4*)eattr;
    for (int i = t; i < n * 4; i += 256) {
        const int row = i >> 2, part = i & 3;
        const int eid = se[row];
        sa4[i] = (eid >= 0) ? ea4[(size_t)eid * 4 + part]
                            : make_float4(0.f, 0.f, 0.f, 0.f);
    }
    __syncthreads();

    for (int slot = wv; slot < n; slot += 4) {
        const int gs = base + slot;
        uint32_t out = 0;
        if (se[slot] >= 0) {
            const float4* sr = (const float4*)&sattr[slot * 16];
            float4 e0 = sr[0], e1 = sr[1], e2 = sr[2], e3 = sr[3];
            const float ef[16] = {e0.x, e0.y, e0.z, e0.w, e1.x, e1.y, e1.z, e1.w,
                                  e2.x, e2.y, e2.z, e2.w, e3.x, e3.y, e3.z, e3.w};
            float d0 = bv.x, d1 = bv.y;
#pragma unroll
            for (int k = 0; k < 16; ++k) {
                d0 = fmaf(ef[k], w[k].x, d0);
                d1 = fmaf(ef[k], w[k].y, d1);
            }
            __half2 hh = __floats2half2_rn(d0, d1);
            out = *reinterpret_cast<uint32_t*>(&hh);
        }
        eab2[(size_t)(gs >> 1) * 128 + lane * 2 + (gs & 1)] = out;
    }
}

// ---------------------------------------------------------------------------
// prepack W1/W2/W_enc into MFMA B-fragment order (f16).
// frag f = kb*8+tc; element: k = kb*32+(lane>>4)*8+i, col = tc*16+(lane&15).
// Wpk[(lm*32+f)*512 + lane*8 + i], lm in [0,2L]: W1 layers, W2 layers, W_enc.
// ---------------------------------------------------------------------------
__global__ void prepack_w(const float* __restrict__ W1, const float* __restrict__ W2,
                          const float* __restrict__ Wenc,
                          _Float16* __restrict__ Wpk, int L)
{
    int tid = blockIdx.x * blockDim.x + threadIdx.x;
    const int total = (2 * L + 1) * 32 * 64;
    if (tid >= total) return;
    const int lane = tid & 63;
    const int f = (tid >> 6) & 31;
    const int lm = tid >> 11;
    const int kb = f >> 3, tc = f & 7;
    const float* src = (lm < L) ? (W1 + (size_t)lm * 16384)
                    : (lm < 2 * L) ? (W2 + (size_t)(lm - L) * 16384)
                    : Wenc;
    _Float16* dst = Wpk + ((size_t)lm * 32 + f) * 512 + lane * 8;
#pragma unroll
    for (int i = 0; i < 8; ++i) {
        const int k = kb * 32 + (lane >> 4) * 8 + i;
        const int col = tc * 16 + (lane & 15);
        dst[i] = (_Float16)src[k * 128 + col];
    }
}

// f32 -> f16 bulk convert (8 elems/thread)
__global__ void cvt_f16(const float* __restrict__ x, _Float16* __restrict__ y, int n8)
{
    int i = blockIdx.x * blockDim.x + threadIdx.x;
    const int st = gridDim.x * blockDim.x;
    for (; i < n8; i += st) {
        float4 a = ((const float4*)x)[2 * i];
        float4 b = ((const float4*)x)[2 * i + 1];
        f16x8 v = {(_Float16)a.x, (_Float16)a.y, (_Float16)a.z, (_Float16)a.w,
                   (_Float16)b.x, (_Float16)b.y, (_Float16)b.z, (_Float16)b.w};
        ((f16x8*)y)[i] = v;
    }
}

// ---------------------------------------------------------------------------
// Encoder MFMA: h16 = x16 @ W_enc + b_enc.
// 256 thr = 4 waves; wave w: 16 rows; 8 tile-cols; K=128 (4 kb).
// ---------------------------------------------------------------------------
__global__ __launch_bounds__(256) void enc_mfma(
    const _Float16* __restrict__ x16, const _Float16* __restrict__ Wpk,
    const float* __restrict__ bias, _Float16* __restrict__ h16, int n)
{
    const int t = threadIdx.x;
    const int lane = t & 63;
    const int w = t >> 6;
    const int row0 = blockIdx.x * 64;
    const int lr = lane & 15;
    const int lg = lane >> 4;

    f32x4 acc[8];
#pragma unroll
    for (int tc = 0; tc < 8; ++tc) acc[tc] = (f32x4){0.f, 0.f, 0.f, 0.f};
    const int arow = min(row0 + w * 16 + lr, n - 1);
#pragma unroll
    for (int kb = 0; kb < 4; ++kb) {
        f16x8 a = *(const f16x8*)&x16[(size_t)arow * 128 + kb * 32 + lg * 8];
#pragma unroll
        for (int tc = 0; tc < 8; ++tc) {
            f16x8 b = *(const f16x8*)&Wpk[((kb * 8 + tc) * 64 + lane) * 8];
            acc[tc] = __builtin_amdgcn_mfma_f32_16x16x32_f16(a, b, acc[tc], 0, 0, 0);
        }
    }
#pragma unroll
    for (int tc = 0; tc < 8; ++tc) {
        const int col = tc * 16 + lr;
        const float bb = bias[col];
#pragma unroll
        for (int j = 0; j < 4; ++j) {
            const int row = row0 + w * 16 + lg * 4 + j;
            if (row < n)
                h16[(size_t)row * 128 + col] = (_Float16)(acc[tc][j] + bb);
        }
    }
}

// ---------------------------------------------------------------------------
// Aggregation: one wave per node, lane owns 2 cols. h16 gather; writes z16.
// ---------------------------------------------------------------------------
__global__ __launch_bounds__(256) void agg_f16(
    const _Float16* __restrict__ h16, const float2* __restrict__ sat,
    const uint32_t* __restrict__ eab2, const int* __restrict__ off,
    _Float16* __restrict__ z16, const float* __restrict__ eps, int layer, int N)
{
    const int t = threadIdx.x;
    const int v = blockIdx.x * 4 + (t >> 6);
    if (v >= N) return;
    const int lane = t & 63;
    const int c = lane * 2;

    const int e0 = off[v], e1 = off[v + 1];   // even-aligned, even length
    float a0 = 0.f, a1 = 0.f;
    int e = e0;
    for (; e + 8 <= e1; e += 8) {
        float4 sa[4];
#pragma unroll
        for (int j = 0; j < 4; ++j) sa[j] = *(const float4*)&sat[e + 2 * j];
        uint2 eb[4];
#pragma unroll
        for (int j = 0; j < 4; ++j)
            eb[j] = *(const uint2*)&eab2[(size_t)((e >> 1) + j) * 128 + lane * 2];
        uint32_t hv[8];
#pragma unroll
        for (int j = 0; j < 4; ++j) {
            hv[2 * j]     = *(const uint32_t*)&h16[(size_t)__float_as_int(sa[j].x) * 128 + c];
            hv[2 * j + 1] = *(const uint32_t*)&h16[(size_t)__float_as_int(sa[j].z) * 128 + c];
        }
#pragma unroll
        for (int j = 0; j < 4; ++j) {
            __half2 hh0 = *reinterpret_cast<const __half2*>(&hv[2 * j]);
            __half2 q0 = *reinterpret_cast<const __half2*>(&eb[j].x);
            a0 += fmaxf(__half2float(__low2half(hh0)) + __half2float(__low2half(q0)), 0.f) * sa[j].y;
            a1 += fmaxf(__half2float(__high2half(hh0)) + __half2float(__high2half(q0)), 0.f) * sa[j].y;
            __half2 hh1 = *reinterpret_cast<const __half2*>(&hv[2 * j + 1]);
            __half2 q1 = *reinterpret_cast<const __half2*>(&eb[j].y);
            a0 += fmaxf(__half2float(__low2half(hh1)) + __half2float(__low2half(q1)), 0.f) * sa[j].w;
            a1 += fmaxf(__half2float(__high2half(hh1)) + __half2float(__high2half(q1)), 0.f) * sa[j].w;
        }
    }
    for (; e < e1; e += 2) {
        float4 sa = *(const float4*)&sat[e];
        uint2 eb = *(const uint2*)&eab2[(size_t)(e >> 1) * 128 + lane * 2];
        uint32_t h0 = *(const uint32_t*)&h16[(size_t)__float_as_int(sa.x) * 128 + c];
        uint32_t h1 = *(const uint32_t*)&h16[(size_t)__float_as_int(sa.z) * 128 + c];
        __half2 hh0 = *reinterpret_cast<const __half2*>(&h0);
        __half2 q0 = *reinterpret_cast<const __half2*>(&eb.x);
        a0 += fmaxf(__half2float(__low2half(hh0)) + __half2float(__low2half(q0)), 0.f) * sa.y;
        a1 += fmaxf(__half2float(__high2half(hh0)) + __half2float(__high2half(q0)), 0.f) * sa.y;
        __half2 hh1 = *reinterpret_cast<const __half2*>(&h1);
        __half2 q1 = *reinterpret_cast<const __half2*>(&eb.y);
        a0 += fmaxf(__half2float(__low2half(hh1)) + __half2float(__low2half(q1)), 0.f) * sa.w;
        a1 += fmaxf(__half2float(__high2half(hh1)) + __half2float(__high2half(q1)), 0.f) * sa.w;
    }

    const float sc = 1.0f + eps[layer];
    uint32_t hv = *(const uint32_t*)&h16[(size_t)v * 128 + c];
    __half2 hh = *reinterpret_cast<const __half2*>(&hv);
    float zx = fmaf(sc, __half2float(__low2half(hh)), a0);
    float zy = fmaf(sc, __half2float(__high2half(hh)), a1);
    __half2 zz = __floats2half2_rn(zx, zy);
    *reinterpret_cast<__half2*>(&z16[(size_t)v * 128 + c]) = zz;
}

// ---------------------------------------------------------------------------
// MFMA MLP: out = relu( relu(BN(z16@W1+b1)) @ W2 + b2 ).
// last==0: write h16 (f16); last==1: write f32 H.
// ---------------------------------------------------------------------------
__global__ __launch_bounds__(256) void mlp_mfma(
    const _Float16* __restrict__ z16,
    const _Float16* __restrict__ W1pk, const float* __restrict__ b1,
    const float* __restrict__ gam, const float* __restrict__ bet,
    const float* __restrict__ mu, const float* __restrict__ var,
    const _Float16* __restrict__ W2pk, const float* __restrict__ b2,
    _Float16* __restrict__ h16out, float* __restrict__ H, int last, int n)
{
    __shared__ _Float16 Yt[64][136];   // padded: 2-way banks
    const int t = threadIdx.x;
    const int lane = t & 63;
    const int w = t >> 6;
    const int row0 = blockIdx.x * 64;
    const int lr = lane & 15;
    const int lg = lane >> 4;

    // ---- GEMM1: z @ W1 ----
    f32x4 acc[8];
#pragma unroll
    for (int tc = 0; tc < 8; ++tc) acc[tc] = (f32x4){0.f, 0.f, 0.f, 0.f};
    const int arow = min(row0 + w * 16 + lr, n - 1);
#pragma unroll
    for (int kb = 0; kb < 4; ++kb) {
        f16x8 a = *(const f16x8*)&z16[(size_t)arow * 128 + kb * 32 + lg * 8];
#pragma unroll
        for (int tc = 0; tc < 8; ++tc) {
            f16x8 b = *(const f16x8*)&W1pk[((kb * 8 + tc) * 64 + lane) * 8];
            acc[tc] = __builtin_amdgcn_mfma_f32_16x16x32_f16(a, b, acc[tc], 0, 0, 0);
        }
    }
    // BN + ReLU -> Yt (f16)
#pragma unroll
    for (int tc = 0; tc < 8; ++tc) {
        const int col = tc * 16 + lr;
        const float s  = gam[col] * rsqrtf(var[col] + 1e-5f);
        const float sh = bet[col] - mu[col] * s;
        const float bb = b1[col];
#pragma unroll
        for (int j = 0; j < 4; ++j) {
            float y = fmaxf(fmaf(acc[tc][j] + bb, s, sh), 0.f);
            Yt[w * 16 + lg * 4 + j][col] = (_Float16)y;
        }
    }
    __syncthreads();

    // ---- GEMM2: Y @ W2 ----
#pragma unroll
    for (int tc = 0; tc < 8; ++tc) acc[tc] = (f32x4){0.f, 0.f, 0.f, 0.f};
#pragma unroll
    for (int kb = 0; kb < 4; ++kb) {
        f16x8 a = *(const f16x8*)&Yt[w * 16 + lr][kb * 32 + lg * 8];
#pragma unroll
        for (int tc = 0; tc < 8; ++tc) {
            f16x8 b = *(const f16x8*)&W2pk[((kb * 8 + tc) * 64 + lane) * 8];
            acc[tc] = __builtin_amdgcn_mfma_f32_16x16x32_f16(a, b, acc[tc], 0, 0, 0);
        }
    }
#pragma unroll
    for (int tc = 0; tc < 8; ++tc) {
        const int col = tc * 16 + lr;
        const float bb = b2[col];
#pragma unroll
        for (int j = 0; j < 4; ++j) {
            const int row = row0 + w * 16 + lg * 4 + j;
            if (row < n) {
                const float o = fmaxf(acc[tc][j] + bb, 0.f);
                if (last) H[(size_t)row * 128 + col] = o;
                else      h16out[(size_t)row * 128 + col] = (_Float16)o;
            }
        }
    }
}

// ---------------------------------------------------------------------------
// Fallback tier (f32 end-to-end): gemm_enc + scale_init + atomic + gemm_mlp
// ---------------------------------------------------------------------------
__global__ __launch_bounds__(512, 4) void gemm_enc(
    const float* __restrict__ A, const float* __restrict__ W,
    const float* __restrict__ bias, float* __restrict__ H, int n)
{
    __shared__ float At[64][128];
    __shared__ float Wb[2][16][128];
    const int t = threadIdx.x;
    const int tx = t & 31, ty = t >> 5;

    const int row0 = blockIdx.x * 64;
    const int nrows = min(64, n - row0);
    const int lim = nrows * 32;
    const float4* A4 = (const float4*)(A + (size_t)row0 * 128);
    float4* At4 = (float4*)&At[0][0];
#pragma unroll
    for (int i = 0; i < 4; ++i) {
        int idx = t + 512 * i;
        if (idx < lim) At4[idx] = A4[idx];
    }
    const float4* W4 = (const float4*)W;
    ((float4*)&Wb[0][0][0])[t] = W4[t];
    __syncthreads();

    float acc[4][4] = {};
    for (int c = 0; c < 8; ++c) {
        const int buf = c & 1;
        float4 wnext;
        if (c < 7) wnext = W4[(c + 1) * 512 + t];
#pragma unroll
        for (int g = 0; g < 4; ++g) {
            float4 w4[4];
#pragma unroll
            for (int kk = 0; kk < 4; ++kk) w4[kk] = *(const float4*)&Wb[buf][g * 4 + kk][tx * 4];
#pragma unroll
            for (int r = 0; r < 4; ++r) {
                float4 a = *(const float4*)&At[ty * 4 + r][c * 16 + g * 4];
                float ar[4] = {a.x, a.y, a.z, a.w};
#pragma unroll
                for (int kk = 0; kk < 4; ++kk) {
                    acc[r][0] = fmaf(ar[kk], w4[kk].x, acc[r][0]);
                    acc[r][1] = fmaf(ar[kk], w4[kk].y, acc[r][1]);
                    acc[r][2] = fmaf(ar[kk], w4[kk].z, acc[r][2]);
                    acc[r][3] = fmaf(ar[kk], w4[kk].w, acc[r][3]);
                }
            }
        }
        if (c < 7) ((float4*)&Wb[buf ^ 1][0][0])[t] = wnext;
        __syncthreads();
    }

    const int c0 = tx * 4;
    float bvv[4];
#pragma unroll
    for (int c = 0; c < 4; ++c) bvv[c] = bias[c0 + c];
#pragma unroll
    for (int r = 0; r < 4; ++r) {
        int row = row0 + ty * 4 + r;
        if (row < n) {
            float4 o;
            o.x = acc[r][0] + bvv[0]; o.y = acc[r][1] + bvv[1];
            o.z = acc[r][2] + bvv[2]; o.w = acc[r][3] + bvv[3];
            *(float4*)&H[(size_t)row * 128 + c0] = o;
        }
    }
}

__global__ void scale_init(const float* __restrict__ h, float* __restrict__ z,
                           const float* __restrict__ eps, int layer, int n4)
{
    const float s = 1.0f + eps[layer];
    int i = blockIdx.x * blockDim.x + threadIdx.x;
    const int stride = gridDim.x * blockDim.x;
    const float4* h4 = (const float4*)h;
    float4* z4 = (float4*)z;
    for (; i < n4; i += stride) {
        float4 v = h4[i];
        v.x *= s; v.y *= s; v.z *= s; v.w *= s;
        z4[i] = v;
    }
}

__global__ __launch_bounds__(256) void edge_atomic(
    const float* __restrict__ h, const int* __restrict__ ei,
    const float* __restrict__ eattr, const float* __restrict__ eatten,
    const float* __restrict__ W_ee, const float* __restrict__ b_ee,
    float* __restrict__ Z, int E)
{
    __shared__ float Wee[16][128];
    __shared__ float bee[128];
    const int t = threadIdx.x;
    const float4* We4 = (const float4*)W_ee;
    float4* Ws4 = (float4*)&Wee[0][0];
#pragma unroll
    for (int i = 0; i < 2; ++i) Ws4[t + 256 * i] = We4[t + 256 * i];
    if (t < 128) bee[t] = b_ee[t];
    __syncthreads();

    const int lane = t & 63;
    const int c = lane * 2;
    const long wid = (long)blockIdx.x * 4 + (t >> 6);
    const long nw = (long)gridDim.x * 4;
    for (long e = wid; e < E; e += nw) {
        const int src = ei[e];
        const int dst = ei[E + e];
        const float att = eatten[e];
        union { float4 v4[4]; float f[16]; } ea;
        const float4* eap = (const float4*)(eattr + e * 16);
        ea.v4[0] = eap[0]; ea.v4[1] = eap[1]; ea.v4[2] = eap[2]; ea.v4[3] = eap[3];
        float2 hv = *(const float2*)&h[(size_t)src * 128 + c];
        float e0 = bee[c], e1 = bee[c + 1];
#pragma unroll
        for (int k = 0; k < 16; ++k) {
            float2 w = *(const float2*)&Wee[k][c];
            e0 = fmaf(ea.f[k], w.x, e0);
            e1 = fmaf(ea.f[k], w.y, e1);
        }
        float m0 = fmaxf(hv.x + e0, 0.f) * att;
        float m1 = fmaxf(hv.y + e1, 0.f) * att;
        atomic_add2(&Z[(size_t)dst * 128 + c], m0, m1);
    }
}

__global__ __launch_bounds__(512, 4) void gemm_mlp(
    const float* __restrict__ Z,
    const float* __restrict__ W1, const float* __restrict__ b1,
    const float* __restrict__ gam, const float* __restrict__ bet,
    const float* __restrict__ mu, const float* __restrict__ var,
    const float* __restrict__ W2, const float* __restrict__ b2,
    float* __restrict__ H, int n)
{
    __shared__ float At[64][128];
    __shared__ float Wb[2][16][128];
    const int t = threadIdx.x;
    const int tx = t & 31, ty = t >> 5;

    const int row0 = blockIdx.x * 64;
    const int nrows = min(64, n - row0);
    const int lim = nrows * 32;
    const float4* Z4 = (const float4*)(Z + (size_t)row0 * 128);
    float4* At4 = (float4*)&At[0][0];
#pragma unroll
    for (int i = 0; i < 4; ++i) {
        int idx = t + 512 * i;
        if (idx < lim) At4[idx] = Z4[idx];
    }
    const float4* W14 = (const float4*)W1;
    ((float4*)&Wb[0][0][0])[t] = W14[t];
    __syncthreads();

    float acc[4][4] = {};
    for (int c = 0; c < 8; ++c) {
        const int buf = c & 1;
        float4 wnext;
        if (c < 7) wnext = W14[(c + 1) * 512 + t];
#pragma unroll
        for (int g = 0; g < 4; ++g) {
            float4 w4[4];
#pragma unroll
            for (int kk = 0; kk < 4; ++kk) w4[kk] = *(const float4*)&Wb[buf][g * 4 + kk][tx * 4];
#pragma unroll
            for (int r = 0; r < 4; ++r) {
                float4 a = *(const float4*)&At[ty * 4 + r][c * 16 + g * 4];
                float ar[4] = {a.x, a.y, a.z, a.w};
#pragma unroll
                for (int kk = 0; kk < 4; ++kk) {
                    acc[r][0] = fmaf(ar[kk], w4[kk].x, acc[r][0]);
                    acc[r][1] = fmaf(ar[kk], w4[kk].y, acc[r][1]);
                    acc[r][2] = fmaf(ar[kk], w4[kk].z, acc[r][2]);
                    acc[r][3] = fmaf(ar[kk], w4[kk].w, acc[r][3]);
                }
            }
        }
        if (c < 7) ((float4*)&Wb[buf ^ 1][0][0])[t] = wnext;
        __syncthreads();
    }

    const int c0 = tx * 4;
    const float4* W24 = (const float4*)W2;
    float4 w2pre = W24[t];
    {
        float b1v[4], scv[4], shv[4];
#pragma unroll
        for (int cl = 0; cl < 4; ++cl) {
            b1v[cl] = b1[c0 + cl];
            float s = gam[c0 + cl] * rsqrtf(var[c0 + cl] + 1e-5f);
            scv[cl] = s;
            shv[cl] = bet[c0 + cl] - mu[c0 + cl] * s;
        }
#pragma unroll
        for (int r = 0; r < 4; ++r) {
            float4 y;
            y.x = fmaxf(fmaf(acc[r][0] + b1v[0], scv[0], shv[0]), 0.f);
            y.y = fmaxf(fmaf(acc[r][1] + b1v[1], scv[1], shv[1]), 0.f);
            y.z = fmaxf(fmaf(acc[r][2] + b1v[2], scv[2], shv[2]), 0.f);
            y.w = fmaxf(fmaf(acc[r][3] + b1v[3], scv[3], shv[3]), 0.f);
            *(float4*)&At[ty * 4 + r][c0] = y;
            acc[r][0] = 0.f; acc[r][1] = 0.f; acc[r][2] = 0.f; acc[r][3] = 0.f;
        }
    }
    ((float4*)&Wb[0][0][0])[t] = w2pre;
    __syncthreads();

    for (int c = 0; c < 8; ++c) {
        const int buf = c & 1;
        float4 wnext;
        if (c < 7) wnext = W24[(c + 1) * 512 + t];
#pragma unroll
        for (int g = 0; g < 4; ++g) {
            float4 w4[4];
#pragma unroll
            for (int kk = 0; kk < 4; ++kk) w4[kk] = *(const float4*)&Wb[buf][g * 4 + kk][tx * 4];
#pragma unroll
            for (int r = 0; r < 4; ++r) {
                float4 a = *(const float4*)&At[ty * 4 + r][c * 16 + g * 4];
                float ar[4] = {a.x, a.y, a.z, a.w};
#pragma unroll
                for (int kk = 0; kk < 4; ++kk) {
                    acc[r][0] = fmaf(ar[kk], w4[kk].x, acc[r][0]);
                    acc[r][1] = fmaf(ar[kk], w4[kk].y, acc[r][1]);
                    acc[r][2] = fmaf(ar[kk], w4[kk].z, acc[r][2]);
                    acc[r][3] = fmaf(ar[kk], w4[kk].w, acc[r][3]);
                }
            }
        }
        if (c < 7) ((float4*)&Wb[buf ^ 1][0][0])[t] = wnext;
        __syncthreads();
    }

    float b2v[4];
#pragma unroll
    for (int cl = 0; cl < 4; ++cl) b2v[cl] = b2[c0 + cl];
#pragma unroll
    for (int r = 0; r < 4; ++r) {
        int row = row0 + ty * 4 + r;
        if (row < n) {
            float4 o;
            o.x = fmaxf(acc[r][0] + b2v[0], 0.f);
            o.y = fmaxf(acc[r][1] + b2v[1], 0.f);
            o.z = fmaxf(acc[r][2] + b2v[2], 0.f);
            o.w = fmaxf(acc[r][3] + b2v[3], 0.f);
            *(float4*)&H[(size_t)row * 128 + c0] = o;
        }
    }
}

extern "C" void kernel_launch(void* const* d_in, const int* in_sizes, int n_in,
                              void* d_out, int out_size, void* d_ws, size_t ws_size,
                              hipStream_t stream)
{
    const float* x      = (const float*)d_in[0];
    const int*   ei     = (const int*)d_in[1];
    // d_in[2] = batch (unused)
    const float* eattr  = (const float*)d_in[3];
    const float* eatten = (const float*)d_in[4];
    const float* W_enc  = (const float*)d_in[5];
    const float* b_enc  = (const float*)d_in[6];
    const float* W_ee   = (const float*)d_in[7];
    const float* b_ee   = (const float*)d_in[8];
    const float* eps    = (const float*)d_in[9];
    const float* W1     = (const float*)d_in[10];
    const float* b1     = (const float*)d_in[11];
    const float* gam    = (const float*)d_in[12];
    const float* bet    = (const float*)d_in[13];
    const float* mu     = (const float*)d_in[14];
    const float* var    = (const float*)d_in[15];
    const float* W2     = (const float*)d_in[16];
    const float* b2     = (const float*)d_in[17];

    const int N = in_sizes[0] / 128;
    const int E = in_sizes[1] / 2;
    const int L = in_sizes[9];
    const int Scap = E + N;      // max padded slots

    float* hout = (float*)d_out;   // final f32 output

    // workspace layout (main path). x16 aliases z16 (x16 dead after enc).
    char* p = (char*)d_ws;
    _Float16* z16 = (_Float16*)p;       p += ((size_t)N * 128 * 2 + 255) & ~(size_t)255;
    _Float16* h16 = (_Float16*)p;       p += ((size_t)N * 128 * 2 + 255) & ~(size_t)255;
    int* off  = (int*)p;                p += 4 * (size_t)(N + 1);
    int* cur  = (int*)p;                p += 4 * (size_t)N;
    int* cnt  = (int*)p;                p += 4 * (size_t)N;
    int* bsum = (int*)p;                p += 4 * 1024;
    int* eids = (int*)p;                p += 4 * (size_t)Scap;
    p = (char*)(((uintptr_t)p + 255) & ~(uintptr_t)255);
    float2* sat = (float2*)p;           p += 8 * (size_t)Scap;
    p = (char*)(((uintptr_t)p + 255) & ~(uintptr_t)255);
    uint32_t* eab2 = (uint32_t*)p;      p += 512 * (size_t)((Scap + 1) / 2);
    p = (char*)(((uintptr_t)p + 255) & ~(uintptr_t)255);
    _Float16* Wpk = (_Float16*)p;       p += (2 * (size_t)L + 1) * 32 * 512 * 2;
    const size_t need_main = (size_t)(p - (char*)d_ws);

    const bool use_main = ws_size >= need_main;
    const int tiles = (N + 63) / 64;
    const int NB = (N + 1023) / 1024;

    if (use_main) {
        _Float16* x16 = z16;   // alias: x16 dead once layer-0 agg writes z16

        zero_cnt<<<(N + 255) / 256, 256, 0, stream>>>(cnt, N);
        hist_kernel<<<1024, 256, 0, stream>>>(ei, cnt, E);
        scan_pass1<<<NB, 256, 0, stream>>>(cnt, bsum, N);
        scan_pass2<<<1, 256, 0, stream>>>(bsum, off, NB, N);
        scan_pass3<<<NB, 256, 0, stream>>>(cnt, bsum, off, cur, N);
        fill_neg1<<<1024, 256, 0, stream>>>(eids, Scap);
        scatter_kernel<<<1024, 256, 0, stream>>>(ei, cur, eids, E);
        permute_sat<<<1024, 256, 0, stream>>>(ei, eatten, eids, off + N, sat, Scap);
        eabuild_staged<<<(Scap + 255) / 256, 256, 0, stream>>>(
            eids, eattr, W_ee, b_ee, off + N, eab2, Scap);
        prepack_w<<<((2 * L + 1) * 32 * 64 + 255) / 256, 256, 0, stream>>>(
            W1, W2, W_enc, Wpk, L);

        cvt_f16<<<2048, 256, 0, stream>>>(x, x16, N * 128 / 8);
        enc_mfma<<<tiles, 256, 0, stream>>>(
            x16, Wpk + (size_t)(2 * L) * 32 * 512, b_enc, h16, N);

        for (int i = 0; i < L; ++i) {
            agg_f16<<<(N + 3) / 4, 256, 0, stream>>>(
                h16, sat, eab2, off, z16, eps, i, N);
            mlp_mfma<<<tiles, 256, 0, stream>>>(
                z16,
                Wpk + (size_t)i * 32 * 512, b1 + i * 128,
                gam + i * 128, bet + i * 128, mu + i * 128, var + i * 128,
                Wpk + (size_t)(L + i) * 32 * 512, b2 + i * 128,
                h16, hout, (i == L - 1) ? 1 : 0, N);
        }
        return;
    }

    // fallback: f32 atomic tier (zbuf at ws start)
    float* zbuf = (float*)d_ws;
    float* h = hout;
    gemm_enc<<<tiles, 512, 0, stream>>>(x, W_enc, b_enc, h, N);
    for (int i = 0; i < L; ++i) {
        scale_init<<<2048, 256, 0, stream>>>(h, zbuf, eps, i, N * 128 / 4);
        edge_atomic<<<2048, 256, 0, stream>>>(h, ei, eattr, eatten, W_ee, b_ee, zbuf, E);
        gemm_mlp<<<tiles, 512, 0, stream>>>(
            zbuf, W1 + (size_t)i * 128 * 128, b1 + i * 128,
            gam + i * 128, bet + i * 128, mu + i * 128, var + i * 128,
            W2 + (size_t)i * 128 * 128, b2 + i * 128,
            h, N);
    }
}